// Round 1
// baseline (1866.381 us; speedup 1.0000x reference)
//
#include <hip/hip_runtime.h>
#include <cstdio>
#include <cstddef>

// ---------------------------------------------------------------------------
// DeformableTransformerDecoderLayer — round 0: correctness-first f32 pipeline.
// bs=8 nq=100 npts=16 C=256 heads=8 hd=32 levels=4 points=4 ffn=1024
// ---------------------------------------------------------------------------

constexpr int CDIM     = 256;
constexpr int M_ROWS   = 12800;        // bs*nq*npts
constexpr int SRC_ROWS = 8 * 19947;    // 159576
constexpr float LN_EPS = 1e-5f;
constexpr float SCALE_HD = 0.17677669529663687f; // 32^-0.5

// ---------------- elementwise add (float4) ----------------
__global__ __launch_bounds__(256) void k_add4(const float4* __restrict__ a,
    const float4* __restrict__ b, float4* __restrict__ o, int n4)
{
  int i = blockIdx.x * 256 + threadIdx.x;
  if (i < n4) {
    float4 x = a[i], y = b[i];
    o[i] = make_float4(x.x + y.x, x.y + y.y, x.z + y.z, x.w + y.w);
  }
}

// ---------------- generic SGEMM: C[m,n] = sum_k A[m,k]*W[n,k] + bias[n] ----
// 64x64 tile, BK=16, 256 threads, each thread 4x4.
__global__ __launch_bounds__(256) void sgemm_bias(
    const float* __restrict__ A, const float* __restrict__ W,
    const float* __restrict__ bias, float* __restrict__ C,
    int M, int N, int K, int relu)
{
  __shared__ float As[16][68];
  __shared__ float Bs[16][68];
  const int m0 = blockIdx.y * 64;
  const int n0 = blockIdx.x * 64;
  const int tid = threadIdx.x;
  const int tx = tid & 15, ty = tid >> 4;
  const int lr = tid >> 2;          // 0..63
  const int lc = (tid & 3) << 2;    // 0,4,8,12
  float acc[4][4] = {};
  for (int k0 = 0; k0 < K; k0 += 16) {
    int m = m0 + lr;
    float4 av = make_float4(0.f, 0.f, 0.f, 0.f);
    if (m < M) av = *(const float4*)(A + (size_t)m * K + k0 + lc);
    As[lc + 0][lr] = av.x; As[lc + 1][lr] = av.y;
    As[lc + 2][lr] = av.z; As[lc + 3][lr] = av.w;
    int n = n0 + lr;
    float4 wv = make_float4(0.f, 0.f, 0.f, 0.f);
    if (n < N) wv = *(const float4*)(W + (size_t)n * K + k0 + lc);
    Bs[lc + 0][lr] = wv.x; Bs[lc + 1][lr] = wv.y;
    Bs[lc + 2][lr] = wv.z; Bs[lc + 3][lr] = wv.w;
    __syncthreads();
#pragma unroll
    for (int kk = 0; kk < 16; kk++) {
      float4 a4 = *(const float4*)&As[kk][ty << 2];
      float4 b4 = *(const float4*)&Bs[kk][tx << 2];
      float a[4] = {a4.x, a4.y, a4.z, a4.w};
      float b[4] = {b4.x, b4.y, b4.z, b4.w};
#pragma unroll
      for (int i = 0; i < 4; i++)
#pragma unroll
        for (int j = 0; j < 4; j++)
          acc[i][j] += a[i] * b[j];
    }
    __syncthreads();
  }
#pragma unroll
  for (int i = 0; i < 4; i++) {
    int m = m0 + (ty << 2) + i;
    if (m >= M) continue;
#pragma unroll
    for (int j = 0; j < 4; j++) {
      int n = n0 + (tx << 2) + j;
      if (n >= N) continue;
      float v = acc[i][j] + bias[n];
      if (relu) v = fmaxf(v, 0.f);
      C[(size_t)m * N + n] = v;
    }
  }
}

// ---------------- intra attention: 800 seqs of L=16, 8 heads --------------
// block = one (seq b', head h). qp/kp/vp rows: b'*16+l, channel h*32+d.
__global__ __launch_bounds__(256) void k_attn_intra(
    const float* __restrict__ qp, const float* __restrict__ kp,
    const float* __restrict__ vp, float* __restrict__ o)
{
  const int blk = blockIdx.x;      // 0..6399
  const int bp = blk >> 3;
  const int h = blk & 7;
  __shared__ float qs[16][32], ks[16][32], vs[16][32];
  __shared__ float ps[16][17];
  const int t = threadIdx.x;
  for (int e = t; e < 512; e += 256) {
    int l = e >> 5, d = e & 31;
    size_t idx = ((size_t)(bp * 16 + l)) * CDIM + h * 32 + d;
    qs[l][d] = qp[idx]; ks[l][d] = kp[idx]; vs[l][d] = vp[idx];
  }
  __syncthreads();
  {
    int i = t >> 4, j = t & 15;
    float s = 0.f;
#pragma unroll
    for (int d = 0; d < 32; d++) s += qs[i][d] * ks[j][d];
    ps[i][j] = s * SCALE_HD;
  }
  __syncthreads();
  if (t < 16) {
    float m = -1e30f;
#pragma unroll
    for (int j = 0; j < 16; j++) m = fmaxf(m, ps[t][j]);
    float sum = 0.f;
#pragma unroll
    for (int j = 0; j < 16; j++) { float e = __expf(ps[t][j] - m); ps[t][j] = e; sum += e; }
    float inv = 1.f / sum;
#pragma unroll
    for (int j = 0; j < 16; j++) ps[t][j] *= inv;
  }
  __syncthreads();
  for (int e = t; e < 512; e += 256) {
    int i = e >> 5, d = e & 31;
    float acc = 0.f;
#pragma unroll
    for (int j = 0; j < 16; j++) acc += ps[i][j] * vs[j][d];
    o[((size_t)(bp * 16 + i)) * CDIM + h * 32 + d] = acc;
  }
}

// ---------------- inter attention: 128 seqs of L=100, 8 heads -------------
// block = one (seq b'', head). rows: b''*100+q, channel h*32+d.
__global__ __launch_bounds__(256) void k_attn_inter(
    const float* __restrict__ qp, const float* __restrict__ kp,
    const float* __restrict__ vp, float* __restrict__ o)
{
  const int blk = blockIdx.x;      // 0..1023
  const int bb = blk >> 3;
  const int h = blk & 7;
  __shared__ float ks[100][32], vs[100][32];
  const int t = threadIdx.x;
  for (int e = t; e < 3200; e += 256) {
    int r = e >> 5, d = e & 31;
    size_t idx = ((size_t)(bb * 100 + r)) * CDIM + h * 32 + d;
    ks[r][d] = kp[idx]; vs[r][d] = vp[idx];
  }
  __syncthreads();
  if (t < 100) {
    float q[32];
    const size_t qidx = ((size_t)(bb * 100 + t)) * CDIM + h * 32;
#pragma unroll
    for (int d = 0; d < 32; d++) q[d] = qp[qidx + d] * SCALE_HD;
    float m = -1e30f;
    for (int j = 0; j < 100; j++) {
      float s = 0.f;
#pragma unroll
      for (int d = 0; d < 32; d++) s += q[d] * ks[j][d];
      m = fmaxf(m, s);
    }
    float acc[32];
#pragma unroll
    for (int d = 0; d < 32; d++) acc[d] = 0.f;
    float sum = 0.f;
    for (int j = 0; j < 100; j++) {
      float s = 0.f;
#pragma unroll
      for (int d = 0; d < 32; d++) s += q[d] * ks[j][d];
      float e = __expf(s - m);
      sum += e;
#pragma unroll
      for (int d = 0; d < 32; d++) acc[d] += e * vs[j][d];
    }
    float inv = 1.f / sum;
#pragma unroll
    for (int d = 0; d < 32; d++) o[qidx + d] = acc[d] * inv;
  }
}

// ---------------- circular conv (k=9, circular pad 4) + BN + ReLU ---------
// x: [800][16][256] (row = b'*16+l), out same layout. block = one b'.
__global__ __launch_bounds__(256) void k_conv(
    const float* __restrict__ x, const float* __restrict__ cw,
    const float* __restrict__ cb, const float* __restrict__ bg,
    const float* __restrict__ bbias, const float* __restrict__ bm,
    const float* __restrict__ bv, float* __restrict__ out)
{
  __shared__ float xs[16][256];
  const int bp = blockIdx.x;
  const int c = threadIdx.x;
  for (int e = threadIdx.x; e < 4096; e += 256) {
    int l = e >> 8, ci = e & 255;
    xs[l][ci] = x[((size_t)bp * 16 + l) * CDIM + ci];
  }
  __syncthreads();
  float acc[16];
  const float cbv = cb[c];
#pragma unroll
  for (int l = 0; l < 16; l++) acc[l] = cbv;
  const float* wrow = cw + (size_t)c * 2304;
  for (int ci = 0; ci < 256; ci++) {
    float xv[16];
#pragma unroll
    for (int l = 0; l < 16; l++) xv[l] = xs[l][ci];
#pragma unroll
    for (int j = 0; j < 9; j++) {
      float w = wrow[ci * 9 + j];
#pragma unroll
      for (int l = 0; l < 16; l++) acc[l] += xv[(l + j + 12) & 15] * w;
    }
  }
  const float s = bg[c] * rsqrtf(bv[c] + LN_EPS);
  const float sh = bbias[c] - bm[c] * s;
#pragma unroll
  for (int l = 0; l < 16; l++) {
    float v = acc[l] * s + sh;
    out[((size_t)bp * 16 + l) * CDIM + c] = fmaxf(v, 0.f);
  }
}

// ---------------- LayerNorm: out[orow] = res[orow]? + LN(a[row]+b[row]) ----
// one wave per row (64 lanes x 4 floats). remap=1: row in ti-layout,
// orow in tgt-layout:  (b*16+p)*100+q  ->  (b*100+q)*16+p
__global__ __launch_bounds__(256) void k_ln(
    const float* __restrict__ a, const float* __restrict__ b,
    const float* __restrict__ res, const float* __restrict__ g,
    const float* __restrict__ beta, float* __restrict__ out, int remap)
{
  const int row = blockIdx.x * 4 + (threadIdx.x >> 6);
  const int lane = threadIdx.x & 63;
  float4 x = ((const float4*)(a + (size_t)row * CDIM))[lane];
  if (b) {
    float4 y = ((const float4*)(b + (size_t)row * CDIM))[lane];
    x.x += y.x; x.y += y.y; x.z += y.z; x.w += y.w;
  }
  float s = x.x + x.y + x.z + x.w;
#pragma unroll
  for (int o = 32; o; o >>= 1) s += __shfl_xor(s, o);
  const float mean = s * (1.f / 256.f);
  float dx = x.x - mean, dy = x.y - mean, dz = x.z - mean, dw = x.w - mean;
  float v = dx * dx + dy * dy + dz * dz + dw * dw;
#pragma unroll
  for (int o = 32; o; o >>= 1) v += __shfl_xor(v, o);
  const float rstd = rsqrtf(v * (1.f / 256.f) + LN_EPS);
  int orow = row;
  if (remap) {
    int bb = row / 1600, rem = row - bb * 1600;
    int p = rem / 100, q = rem - p * 100;
    orow = (bb * 100 + q) * 16 + p;
  }
  const float4 gv = ((const float4*)g)[lane];
  const float4 bv = ((const float4*)beta)[lane];
  float4 r;
  r.x = dx * rstd * gv.x + bv.x;
  r.y = dy * rstd * gv.y + bv.y;
  r.z = dz * rstd * gv.z + bv.z;
  r.w = dw * rstd * gv.w + bv.w;
  if (res) {
    float4 rr = ((const float4*)(res + (size_t)orow * CDIM))[lane];
    r.x += rr.x; r.y += rr.y; r.z += rr.z; r.w += rr.w;
  }
  ((float4*)(out + (size_t)orow * CDIM))[lane] = r;
}

// ---------------- transpose tgt-layout -> ti-layout -----------------------
__global__ __launch_bounds__(256) void k_transpose(
    const float* __restrict__ in, float* __restrict__ out)
{
  const int row = blockIdx.x;                 // ti row: (b*16+p)*100+q
  const int bb = row / 1600, rem = row - bb * 1600;
  const int p = rem / 100, q = rem - p * 100;
  const int src = (bb * 100 + q) * 16 + p;
  out[(size_t)row * CDIM + threadIdx.x] = in[(size_t)src * CDIM + threadIdx.x];
}

// ---------------- MSDA: softmax(aw) + bilinear sample + reduce ------------
__device__ __forceinline__ float msda_corner(const float* __restrict__ v,
    size_t vbase, int Wi, int Hi, int xi, int yi)
{
  bool ok = (xi >= 0) && (xi < Wi) && (yi >= 0) && (yi < Hi);
  int xc = min(max(xi, 0), Wi - 1);
  int yc = min(max(yi, 0), Hi - 1);
  float g = v[vbase + (size_t)(yc * Wi + xc) * 256];
  return ok ? g : 0.f;
}

__global__ __launch_bounds__(256) void k_msda(
    const float* __restrict__ off, const float* __restrict__ awl,
    const float* __restrict__ ref, const float* __restrict__ value,
    float* __restrict__ out)
{
  const int row = blockIdx.x;            // b*1600 + qi
  const int b = row / 1600;
  const int qi = row - b * 1600;
  const int q = qi >> 4;
  const int t = threadIdx.x;
  const int h = t >> 5, d = t & 31;
  const float* aw = awl + (size_t)row * 128 + h * 16;
  float lg[16];
  float m = -1e30f;
#pragma unroll
  for (int s = 0; s < 16; s++) { lg[s] = aw[s]; m = fmaxf(m, lg[s]); }
  float sum = 0.f;
#pragma unroll
  for (int s = 0; s < 16; s++) { lg[s] = __expf(lg[s] - m); sum += lg[s]; }
  const float inv = 1.f / sum;
  const float* offp = off + (size_t)row * 256 + h * 32;
  const int Hs[4] = {100, 50, 25, 13};
  const int Ws[4] = {150, 75, 38, 19};
  const int LS[4] = {0, 15000, 18750, 19700};
  float acc = 0.f;
#pragma unroll
  for (int l = 0; l < 4; l++) {
    const int Wi = Ws[l], Hi = Hs[l];
    const float Wf = (float)Wi, Hf = (float)Hi;
    const float rx = ref[(((size_t)b * 100 + q) * 4 + l) * 2 + 0];
    const float ry = ref[(((size_t)b * 100 + q) * 4 + l) * 2 + 1];
    const size_t vbase = ((size_t)b * 19947 + LS[l]) * 256 + h * 32 + d;
#pragma unroll
    for (int p = 0; p < 4; p++) {
      const int s = l * 4 + p;
      const float locx = rx + offp[2 * s] / Wf;
      const float locy = ry + offp[2 * s + 1] / Hf;
      const float x = locx * Wf - 0.5f;
      const float y = locy * Hf - 0.5f;
      const float x0f = floorf(x), y0f = floorf(y);
      const float lx = x - x0f, ly = y - y0f;
      const int x0 = (int)x0f, y0 = (int)y0f;
      const float v00 = msda_corner(value, vbase, Wi, Hi, x0, y0);
      const float v01 = msda_corner(value, vbase, Wi, Hi, x0 + 1, y0);
      const float v10 = msda_corner(value, vbase, Wi, Hi, x0, y0 + 1);
      const float v11 = msda_corner(value, vbase, Wi, Hi, x0 + 1, y0 + 1);
      const float bil = (v00 * (1.f - lx) + v01 * lx) * (1.f - ly)
                      + (v10 * (1.f - lx) + v11 * lx) * ly;
      acc += (lg[s] * inv) * bil;
    }
  }
  out[(size_t)row * 256 + h * 32 + d] = acc;
}

// ---------------------------------------------------------------------------
extern "C" void kernel_launch(void* const* d_in, const int* in_sizes, int n_in,
                              void* d_out, int out_size, void* d_ws, size_t ws_size,
                              hipStream_t stream)
{
  const float* tgt    = (const float*)d_in[0];
  const float* qpos   = (const float*)d_in[1];
  const float* ref    = (const float*)d_in[2];
  const float* src    = (const float*)d_in[3];
  const float* wqkv_i = (const float*)d_in[4];
  const float* bqkv_i = (const float*)d_in[5];
  const float* wo_i   = (const float*)d_in[6];
  const float* bo_i   = (const float*)d_in[7];
  const float* conv_w = (const float*)d_in[8];
  const float* conv_b = (const float*)d_in[9];
  const float* bn_g   = (const float*)d_in[10];
  const float* bn_b   = (const float*)d_in[11];
  const float* bn_m   = (const float*)d_in[12];
  const float* bn_v   = (const float*)d_in[13];
  const float* ln_ig  = (const float*)d_in[14];
  const float* ln_ib  = (const float*)d_in[15];
  const float* mfw    = (const float*)d_in[16];
  const float* mfb    = (const float*)d_in[17];
  const float* ln_fg  = (const float*)d_in[18];
  const float* ln_fb  = (const float*)d_in[19];
  const float* wqkv_e = (const float*)d_in[20];
  const float* bqkv_e = (const float*)d_in[21];
  const float* wo_e   = (const float*)d_in[22];
  const float* bo_e   = (const float*)d_in[23];
  const float* ln_eg  = (const float*)d_in[24];
  const float* ln_eb  = (const float*)d_in[25];
  const float* w_off  = (const float*)d_in[26];
  const float* b_off  = (const float*)d_in[27];
  const float* w_attn = (const float*)d_in[28];
  const float* b_attn = (const float*)d_in[29];
  const float* w_val  = (const float*)d_in[30];
  const float* b_val  = (const float*)d_in[31];
  const float* w_out  = (const float*)d_in[32];
  const float* b_out  = (const float*)d_in[33];
  const float* ln_cg  = (const float*)d_in[34];
  const float* ln_cb  = (const float*)d_in[35];
  const float* w1     = (const float*)d_in[36];
  const float* b1     = (const float*)d_in[37];
  const float* w2     = (const float*)d_in[38];
  const float* b2     = (const float*)d_in[39];
  const float* ln3g   = (const float*)d_in[40];
  const float* ln3b   = (const float*)d_in[41];

  float* out = (float*)d_out;
  float* ws = (float*)d_ws;
  const size_t MC = (size_t)M_ROWS * CDIM;   // 3,276,800 floats
  float* S[8];
  for (int i = 0; i < 8; i++) S[i] = ws + (size_t)i * MC;
  float* Bbuf = ws + 8 * MC;                        // 12800*1024 floats
  float* V = Bbuf + (size_t)M_ROWS * 1024;          // 159576*256 floats
  const size_t needed = (8 * MC + (size_t)M_ROWS * 1024 +
                         (size_t)SRC_ROWS * CDIM) * sizeof(float);
  if (ws_size < needed) {
    fprintf(stderr, "kernel_launch: workspace too small (%zu < %zu)\n",
            (size_t)ws_size, needed);
    return;
  }

  dim3 blk(256);
  const int n4 = (int)(MC / 4);
  dim3 gadd((n4 + 255) / 256);
  dim3 g256(CDIM / 64, M_ROWS / 64);
  dim3 g128(128 / 64, M_ROWS / 64);
  dim3 g1024(1024 / 64, M_ROWS / 64);
  dim3 gval(CDIM / 64, (SRC_ROWS + 63) / 64);

  // ---- EFSA intra branch ----
  k_add4<<<gadd, blk, 0, stream>>>((const float4*)tgt, (const float4*)qpos,
                                   (float4*)S[0], n4);                       // qk
  sgemm_bias<<<g256, blk, 0, stream>>>(S[0], wqkv_i,             bqkv_i,       S[1], M_ROWS, CDIM, CDIM, 0); // qp
  sgemm_bias<<<g256, blk, 0, stream>>>(S[0], wqkv_i + 256 * 256, bqkv_i + 256, S[2], M_ROWS, CDIM, CDIM, 0); // kp
  sgemm_bias<<<g256, blk, 0, stream>>>(tgt,  wqkv_i + 512 * 256, bqkv_i + 512, S[3], M_ROWS, CDIM, CDIM, 0); // vp
  k_attn_intra<<<800 * 8, blk, 0, stream>>>(S[1], S[2], S[3], S[4]);
  sgemm_bias<<<g256, blk, 0, stream>>>(S[4], wo_i, bo_i, S[5], M_ROWS, CDIM, CDIM, 0); // t_attn
  k_conv<<<800, blk, 0, stream>>>(S[0], conv_w, conv_b, bn_g, bn_b, bn_m, bn_v, S[6]); // t_cc
  k_ln<<<M_ROWS / 4, blk, 0, stream>>>(S[5], S[6], tgt, ln_ig, ln_ib, S[7], 0);        // tgt1
  sgemm_bias<<<g256, blk, 0, stream>>>(S[7], mfw, mfb, S[1], M_ROWS, CDIM, CDIM, 0);   // fuse tmp
  k_ln<<<M_ROWS / 4, blk, 0, stream>>>(S[1], nullptr, S[7], ln_fg, ln_fb, S[0], 0);    // tgt2

  // ---- inter attention ----
  k_transpose<<<M_ROWS, blk, 0, stream>>>(S[0], S[2]);                                 // ti
  sgemm_bias<<<g256, blk, 0, stream>>>(S[2], wqkv_e,             bqkv_e,       S[3], M_ROWS, CDIM, CDIM, 0);
  sgemm_bias<<<g256, blk, 0, stream>>>(S[2], wqkv_e + 256 * 256, bqkv_e + 256, S[4], M_ROWS, CDIM, CDIM, 0);
  sgemm_bias<<<g256, blk, 0, stream>>>(S[2], wqkv_e + 512 * 256, bqkv_e + 512, S[5], M_ROWS, CDIM, CDIM, 0);
  k_attn_inter<<<128 * 8, blk, 0, stream>>>(S[3], S[4], S[5], S[6]);
  sgemm_bias<<<g256, blk, 0, stream>>>(S[6], wo_e, bo_e, S[1], M_ROWS, CDIM, CDIM, 0); // t2
  k_ln<<<M_ROWS / 4, blk, 0, stream>>>(S[2], S[1], nullptr, ln_eg, ln_eb, S[7], 1);    // tgt_inter (remapped)

  // ---- deformable cross attention ----
  k_add4<<<gadd, blk, 0, stream>>>((const float4*)S[7], (const float4*)qpos,
                                   (float4*)S[0], n4);                                 // q_cross
  sgemm_bias<<<gval, blk, 0, stream>>>(src, w_val, b_val, V, SRC_ROWS, CDIM, CDIM, 0); // value
  sgemm_bias<<<g256, blk, 0, stream>>>(S[0], w_off,  b_off,  S[1], M_ROWS, CDIM, CDIM, 0); // off
  sgemm_bias<<<g128, blk, 0, stream>>>(S[0], w_attn, b_attn, S[2], M_ROWS, 128,  CDIM, 0); // aw logits
  k_msda<<<M_ROWS, blk, 0, stream>>>(S[1], S[2], ref, V, S[3]);                        // sampled
  sgemm_bias<<<g256, blk, 0, stream>>>(S[3], w_out, b_out, S[4], M_ROWS, CDIM, CDIM, 0); // t2c
  k_ln<<<M_ROWS / 4, blk, 0, stream>>>(S[7], S[4], nullptr, ln_cg, ln_cb, S[0], 0);    // tgt3

  // ---- FFN ----
  sgemm_bias<<<g1024, blk, 0, stream>>>(S[0], w1, b1, Bbuf, M_ROWS, 1024, CDIM, 1);    // relu(h)
  sgemm_bias<<<g256,  blk, 0, stream>>>(Bbuf, w2, b2, S[1], M_ROWS, CDIM, 1024, 0);    // t2f
  k_ln<<<M_ROWS / 4, blk, 0, stream>>>(S[0], S[1], nullptr, ln3g, ln3b, out, 0);       // output
}

// Round 2
// 1000.072 us; speedup vs baseline: 1.8662x; 1.8662x over previous
//
#include <hip/hip_runtime.h>
#include <cstdio>
#include <cstddef>

// ---------------------------------------------------------------------------
// DeformableTransformerDecoderLayer — round 1: bf16 MFMA GEMMs (m97 structure),
// conv as implicit-im2col MFMA GEMM with fused BN+ReLU, bf16 value for MSDA.
// bs=8 nq=100 npts=16 C=256 heads=8 hd=32 levels=4 points=4 ffn=1024
// ---------------------------------------------------------------------------

constexpr int CDIM     = 256;
constexpr int M_ROWS   = 12800;        // bs*nq*npts
constexpr int SRC_ROWS = 8 * 19947;    // 159576
constexpr int SRC_PAD  = 159616;       // 1247*128
constexpr float LN_EPS = 1e-5f;
constexpr float SCALE_HD = 0.17677669529663687f; // 32^-0.5

typedef unsigned short u16;
typedef __attribute__((ext_vector_type(8))) short short8v;
typedef __attribute__((ext_vector_type(4))) float f32x4;

__device__ __forceinline__ u16 f2b(float f) {
  unsigned u = __float_as_uint(f);
  unsigned r = (u + 0x7fffu + ((u >> 16) & 1u)) >> 16;
  return (u16)r;
}
__device__ __forceinline__ float b2f(u16 h) {
  return __uint_as_float(((unsigned)h) << 16);
}

// ---------------- elementwise add (float4) ----------------
__global__ __launch_bounds__(256) void k_add4(const float4* __restrict__ a,
    const float4* __restrict__ b, float4* __restrict__ o, int n4)
{
  int i = blockIdx.x * 256 + threadIdx.x;
  if (i < n4) {
    float4 x = a[i], y = b[i];
    o[i] = make_float4(x.x + y.x, x.y + y.y, x.z + y.z, x.w + y.w);
  }
}

// ---------------- f32 -> bf16 convert (8 elems/thread) ----------------
__global__ __launch_bounds__(256) void k_f2b8(const float4* __restrict__ in,
    short8v* __restrict__ out, int n8)
{
  int i = blockIdx.x * 256 + threadIdx.x;
  if (i >= n8) return;
  float4 x = in[2 * i], y = in[2 * i + 1];
  short8v r;
  r[0] = (short)f2b(x.x); r[1] = (short)f2b(x.y);
  r[2] = (short)f2b(x.z); r[3] = (short)f2b(x.w);
  r[4] = (short)f2b(y.x); r[5] = (short)f2b(y.y);
  r[6] = (short)f2b(y.z); r[7] = (short)f2b(y.w);
  out[i] = r;
}

// src convert with zero-padding to SRC_PAD rows
__global__ __launch_bounds__(256) void k_src2b(const float4* __restrict__ in,
    short8v* __restrict__ out, int n8_real, int n8_total)
{
  int i = blockIdx.x * 256 + threadIdx.x;
  if (i >= n8_total) return;
  short8v r;
  if (i >= n8_real) {
#pragma unroll
    for (int j = 0; j < 8; j++) r[j] = 0;
  } else {
    float4 x = in[2 * i], y = in[2 * i + 1];
    r[0] = (short)f2b(x.x); r[1] = (short)f2b(x.y);
    r[2] = (short)f2b(x.z); r[3] = (short)f2b(x.w);
    r[4] = (short)f2b(y.x); r[5] = (short)f2b(y.y);
    r[6] = (short)f2b(y.z); r[7] = (short)f2b(y.w);
  }
  out[i] = r;
}

// conv weight reorder: Wc[n][j*256+ci] = conv_w[n][ci][j], bf16
__global__ __launch_bounds__(256) void k_convw(const float* __restrict__ cw,
    u16* __restrict__ wc)
{
  int n = blockIdx.x, ci = threadIdx.x;
  const float* s = cw + (size_t)n * 2304 + (size_t)ci * 9;
#pragma unroll
  for (int j = 0; j < 9; j++)
    wc[(size_t)n * 2304 + j * 256 + ci] = f2b(s[j]);
}

// fold conv bias + BN into scale/shift
__global__ void k_bnfold(const float* __restrict__ cb, const float* __restrict__ g,
    const float* __restrict__ b, const float* __restrict__ m,
    const float* __restrict__ v, float* __restrict__ scale, float* __restrict__ shift)
{
  int c = threadIdx.x;
  float s = g[c] * rsqrtf(v[c] + LN_EPS);
  scale[c] = s;
  shift[c] = (cb[c] - m[c]) * s + b[c];
}

// ---------------- bf16 MFMA GEMM (m97 structure) --------------------------
// C[m,n] = sum_k A[m,k]*W[n,k]; A:[M,K] bf16, W:[N,K] bf16 (row-major).
// 128x128 tile, BK=32, 256 threads = 4 waves (2x2 of 64x64 wave-tiles).
// epilogue: v = acc*scale[n] + bias[n]; optional relu; f32 or bf16 out.
// CONV=1: A is qk_b [800][16][256]; k = j*256+ci; row (b',l) reads
//         qk_b[b'][(l+j-4)&15][ci] — circular im2col folded into staging.
template<int CONV>
__global__ __launch_bounds__(256) void gemm_bf16(
    const u16* __restrict__ A, const u16* __restrict__ W,
    const float* __restrict__ bias, const float* __restrict__ scale,
    float* __restrict__ Cf, u16* __restrict__ Cb,
    int M, int N, int K, int relu)
{
  __shared__ u16 As[4096];
  __shared__ u16 Bs[4096];
  const int tid = threadIdx.x;
  const int w = tid >> 6, l = tid & 63;
  const int m0 = blockIdx.y * 128, n0 = blockIdx.x * 128;
  const int wr = w >> 1, wc = w & 1;
  const int colA = (l & 3) << 3;            // 0,8,16,24
  const int rowBase = (w << 4) + (l >> 2);  // wave rows: w*16 + l/4
  const int lr = l & 15, lk = (l >> 4) << 3;
  f32x4 acc[4][4] = {};

  for (int k0 = 0; k0 < K; k0 += 32) {
#pragma unroll
    for (int i = 0; i < 2; i++) {
      const int row = rowBase + i * 64;
      const u16* ga;
      if (CONV) {
        const int m = m0 + row;
        const int bp = m >> 4, lp = m & 15;
        const int j = k0 >> 8;                 // kernel tap, uniform per K-step
        const int sl = (lp + j + 12) & 15;     // circular shift
        ga = A + (((size_t)(bp << 4) + sl) << 8) + (k0 & 255) + colA;
      } else {
        ga = A + (size_t)(m0 + row) * K + k0 + colA;
      }
      __builtin_amdgcn_global_load_lds(
          (const __attribute__((address_space(1))) void*)ga,
          (__attribute__((address_space(3))) void*)&As[(i << 11) + (w << 9)],
          16, 0, 0);
      const u16* gb = W + (size_t)(n0 + row) * K + k0 + colA;
      __builtin_amdgcn_global_load_lds(
          (const __attribute__((address_space(1))) void*)gb,
          (__attribute__((address_space(3))) void*)&Bs[(i << 11) + (w << 9)],
          16, 0, 0);
    }
    __syncthreads();
    short8v a[4], b[4];
#pragma unroll
    for (int t = 0; t < 4; t++) {
      a[t] = *(const short8v*)&As[((wr << 6) + (t << 4) + lr) * 32 + lk];
      b[t] = *(const short8v*)&Bs[((wc << 6) + (t << 4) + lr) * 32 + lk];
    }
#pragma unroll
    for (int mi = 0; mi < 4; mi++)
#pragma unroll
      for (int ni = 0; ni < 4; ni++)
        acc[mi][ni] = __builtin_amdgcn_mfma_f32_16x16x32_bf16(
            a[mi], b[ni], acc[mi][ni], 0, 0, 0);
    __syncthreads();
  }

  const int lq = l >> 4;
#pragma unroll
  for (int ni = 0; ni < 4; ni++) {
    const int n = n0 + (wc << 6) + (ni << 4) + lr;
    const float bs = bias ? bias[n] : 0.f;
    const float sc = scale ? scale[n] : 1.f;
#pragma unroll
    for (int mi = 0; mi < 4; mi++) {
#pragma unroll
      for (int j = 0; j < 4; j++) {
        const int m = m0 + (wr << 6) + (mi << 4) + (lq << 2) + j;
        float v = acc[mi][ni][j] * sc + bs;
        if (relu) v = fmaxf(v, 0.f);
        if (Cb) Cb[(size_t)m * N + n] = f2b(v);
        else    Cf[(size_t)m * N + n] = v;
      }
    }
  }
}

// ---------------- intra attention: 800 seqs of L=16, 8 heads --------------
__global__ __launch_bounds__(256) void k_attn_intra(
    const float* __restrict__ qp, const float* __restrict__ kp,
    const float* __restrict__ vp, float* __restrict__ o)
{
  const int blk = blockIdx.x;
  const int bp = blk >> 3;
  const int h = blk & 7;
  __shared__ float qs[16][32], ks[16][32], vs[16][32];
  __shared__ float ps[16][17];
  const int t = threadIdx.x;
  for (int e = t; e < 512; e += 256) {
    int l = e >> 5, d = e & 31;
    size_t idx = ((size_t)(bp * 16 + l)) * CDIM + h * 32 + d;
    qs[l][d] = qp[idx]; ks[l][d] = kp[idx]; vs[l][d] = vp[idx];
  }
  __syncthreads();
  {
    int i = t >> 4, j = t & 15;
    float s = 0.f;
#pragma unroll
    for (int d = 0; d < 32; d++) s += qs[i][d] * ks[j][d];
    ps[i][j] = s * SCALE_HD;
  }
  __syncthreads();
  if (t < 16) {
    float m = -1e30f;
#pragma unroll
    for (int j = 0; j < 16; j++) m = fmaxf(m, ps[t][j]);
    float sum = 0.f;
#pragma unroll
    for (int j = 0; j < 16; j++) { float e = __expf(ps[t][j] - m); ps[t][j] = e; sum += e; }
    float inv = 1.f / sum;
#pragma unroll
    for (int j = 0; j < 16; j++) ps[t][j] *= inv;
  }
  __syncthreads();
  for (int e = t; e < 512; e += 256) {
    int i = e >> 5, d = e & 31;
    float acc = 0.f;
#pragma unroll
    for (int j = 0; j < 16; j++) acc += ps[i][j] * vs[j][d];
    o[((size_t)(bp * 16 + i)) * CDIM + h * 32 + d] = acc;
  }
}

// ---------------- inter attention: 128 seqs of L=100, 8 heads -------------
__global__ __launch_bounds__(256) void k_attn_inter(
    const float* __restrict__ qp, const float* __restrict__ kp,
    const float* __restrict__ vp, float* __restrict__ o)
{
  const int blk = blockIdx.x;
  const int bb = blk >> 3;
  const int h = blk & 7;
  __shared__ float ks[100][32], vs[100][32];
  const int t = threadIdx.x;
  for (int e = t; e < 3200; e += 256) {
    int r = e >> 5, d = e & 31;
    size_t idx = ((size_t)(bb * 100 + r)) * CDIM + h * 32 + d;
    ks[r][d] = kp[idx]; vs[r][d] = vp[idx];
  }
  __syncthreads();
  if (t < 100) {
    float q[32];
    const size_t qidx = ((size_t)(bb * 100 + t)) * CDIM + h * 32;
#pragma unroll
    for (int d = 0; d < 32; d++) q[d] = qp[qidx + d] * SCALE_HD;
    float m = -1e30f;
    for (int j = 0; j < 100; j++) {
      float s = 0.f;
#pragma unroll
      for (int d = 0; d < 32; d++) s += q[d] * ks[j][d];
      m = fmaxf(m, s);
    }
    float acc[32];
#pragma unroll
    for (int d = 0; d < 32; d++) acc[d] = 0.f;
    float sum = 0.f;
    for (int j = 0; j < 100; j++) {
      float s = 0.f;
#pragma unroll
      for (int d = 0; d < 32; d++) s += q[d] * ks[j][d];
      float e = __expf(s - m);
      sum += e;
#pragma unroll
      for (int d = 0; d < 32; d++) acc[d] += e * vs[j][d];
    }
    float inv = 1.f / sum;
#pragma unroll
    for (int d = 0; d < 32; d++) o[qidx + d] = acc[d] * inv;
  }
}

// ---------------- LayerNorm (one wave per row) -----------------------------
__global__ __launch_bounds__(256) void k_ln(
    const float* __restrict__ a, const float* __restrict__ b,
    const float* __restrict__ res, const float* __restrict__ g,
    const float* __restrict__ beta, float* __restrict__ out, int remap)
{
  const int row = blockIdx.x * 4 + (threadIdx.x >> 6);
  const int lane = threadIdx.x & 63;
  float4 x = ((const float4*)(a + (size_t)row * CDIM))[lane];
  if (b) {
    float4 y = ((const float4*)(b + (size_t)row * CDIM))[lane];
    x.x += y.x; x.y += y.y; x.z += y.z; x.w += y.w;
  }
  float s = x.x + x.y + x.z + x.w;
#pragma unroll
  for (int o = 32; o; o >>= 1) s += __shfl_xor(s, o);
  const float mean = s * (1.f / 256.f);
  float dx = x.x - mean, dy = x.y - mean, dz = x.z - mean, dw = x.w - mean;
  float v = dx * dx + dy * dy + dz * dz + dw * dw;
#pragma unroll
  for (int o = 32; o; o >>= 1) v += __shfl_xor(v, o);
  const float rstd = rsqrtf(v * (1.f / 256.f) + LN_EPS);
  int orow = row;
  if (remap) {
    int bb = row / 1600, rem = row - bb * 1600;
    int p = rem / 100, q = rem - p * 100;
    orow = (bb * 100 + q) * 16 + p;
  }
  const float4 gv = ((const float4*)g)[lane];
  const float4 bv = ((const float4*)beta)[lane];
  float4 r;
  r.x = dx * rstd * gv.x + bv.x;
  r.y = dy * rstd * gv.y + bv.y;
  r.z = dz * rstd * gv.z + bv.z;
  r.w = dw * rstd * gv.w + bv.w;
  if (res) {
    float4 rr = ((const float4*)(res + (size_t)orow * CDIM))[lane];
    r.x += rr.x; r.y += rr.y; r.z += rr.z; r.w += rr.w;
  }
  ((float4*)(out + (size_t)orow * CDIM))[lane] = r;
}

// ---------------- transpose tgt-layout -> ti-layout -----------------------
__global__ __launch_bounds__(256) void k_transpose(
    const float* __restrict__ in, float* __restrict__ out)
{
  const int row = blockIdx.x;
  const int bb = row / 1600, rem = row - bb * 1600;
  const int p = rem / 100, q = rem - p * 100;
  const int src = (bb * 100 + q) * 16 + p;
  out[(size_t)row * CDIM + threadIdx.x] = in[(size_t)src * CDIM + threadIdx.x];
}

// ---------------- MSDA: softmax(aw) + bilinear sample + reduce ------------
__device__ __forceinline__ float msda_corner(const u16* __restrict__ v,
    size_t vbase, int Wi, int Hi, int xi, int yi)
{
  bool ok = (xi >= 0) && (xi < Wi) && (yi >= 0) && (yi < Hi);
  int xc = min(max(xi, 0), Wi - 1);
  int yc = min(max(yi, 0), Hi - 1);
  float g = b2f(v[vbase + (size_t)(yc * Wi + xc) * 256]);
  return ok ? g : 0.f;
}

__global__ __launch_bounds__(256) void k_msda(
    const float* __restrict__ off, const float* __restrict__ awl,
    const float* __restrict__ ref, const u16* __restrict__ value,
    float* __restrict__ out)
{
  const int row = blockIdx.x;            // b*1600 + qi
  const int b = row / 1600;
  const int qi = row - b * 1600;
  const int q = qi >> 4;
  const int t = threadIdx.x;
  const int h = t >> 5, d = t & 31;
  const float* aw = awl + (size_t)row * 128 + h * 16;
  float lg[16];
  float m = -1e30f;
#pragma unroll
  for (int s = 0; s < 16; s++) { lg[s] = aw[s]; m = fmaxf(m, lg[s]); }
  float sum = 0.f;
#pragma unroll
  for (int s = 0; s < 16; s++) { lg[s] = __expf(lg[s] - m); sum += lg[s]; }
  const float inv = 1.f / sum;
  const float* offp = off + (size_t)row * 256 + h * 32;
  const int Hs[4] = {100, 50, 25, 13};
  const int Ws[4] = {150, 75, 38, 19};
  const int LS[4] = {0, 15000, 18750, 19700};
  float acc = 0.f;
#pragma unroll
  for (int l = 0; l < 4; l++) {
    const int Wi = Ws[l], Hi = Hs[l];
    const float Wf = (float)Wi, Hf = (float)Hi;
    const float rx = ref[(((size_t)b * 100 + q) * 4 + l) * 2 + 0];
    const float ry = ref[(((size_t)b * 100 + q) * 4 + l) * 2 + 1];
    const size_t vbase = ((size_t)b * 19947 + LS[l]) * 256 + h * 32 + d;
#pragma unroll
    for (int p = 0; p < 4; p++) {
      const int s = l * 4 + p;
      const float locx = rx + offp[2 * s] / Wf;
      const float locy = ry + offp[2 * s + 1] / Hf;
      const float x = locx * Wf - 0.5f;
      const float y = locy * Hf - 0.5f;
      const float x0f = floorf(x), y0f = floorf(y);
      const float lx = x - x0f, ly = y - y0f;
      const int x0 = (int)x0f, y0 = (int)y0f;
      const float v00 = msda_corner(value, vbase, Wi, Hi, x0, y0);
      const float v01 = msda_corner(value, vbase, Wi, Hi, x0 + 1, y0);
      const float v10 = msda_corner(value, vbase, Wi, Hi, x0, y0 + 1);
      const float v11 = msda_corner(value, vbase, Wi, Hi, x0 + 1, y0 + 1);
      const float bil = (v00 * (1.f - lx) + v01 * lx) * (1.f - ly)
                      + (v10 * (1.f - lx) + v11 * lx) * ly;
      acc += (lg[s] * inv) * bil;
    }
  }
  out[(size_t)row * 256 + h * 32 + d] = acc;
}

// ---------------------------------------------------------------------------
extern "C" void kernel_launch(void* const* d_in, const int* in_sizes, int n_in,
                              void* d_out, int out_size, void* d_ws, size_t ws_size,
                              hipStream_t stream)
{
  const float* tgt    = (const float*)d_in[0];
  const float* qpos   = (const float*)d_in[1];
  const float* ref    = (const float*)d_in[2];
  const float* src    = (const float*)d_in[3];
  const float* wqkv_i = (const float*)d_in[4];
  const float* bqkv_i = (const float*)d_in[5];
  const float* wo_i   = (const float*)d_in[6];
  const float* bo_i   = (const float*)d_in[7];
  const float* conv_w = (const float*)d_in[8];
  const float* conv_b = (const float*)d_in[9];
  const float* bn_g   = (const float*)d_in[10];
  const float* bn_b   = (const float*)d_in[11];
  const float* bn_m   = (const float*)d_in[12];
  const float* bn_v   = (const float*)d_in[13];
  const float* ln_ig  = (const float*)d_in[14];
  const float* ln_ib  = (const float*)d_in[15];
  const float* mfw    = (const float*)d_in[16];
  const float* mfb    = (const float*)d_in[17];
  const float* ln_fg  = (const float*)d_in[18];
  const float* ln_fb  = (const float*)d_in[19];
  const float* wqkv_e = (const float*)d_in[20];
  const float* bqkv_e = (const float*)d_in[21];
  const float* wo_e   = (const float*)d_in[22];
  const float* bo_e   = (const float*)d_in[23];
  const float* ln_eg  = (const float*)d_in[24];
  const float* ln_eb  = (const float*)d_in[25];
  const float* w_off  = (const float*)d_in[26];
  const float* b_off  = (const float*)d_in[27];
  const float* w_attn = (const float*)d_in[28];
  const float* b_attn = (const float*)d_in[29];
  const float* w_val  = (const float*)d_in[30];
  const float* b_val  = (const float*)d_in[31];
  const float* w_out  = (const float*)d_in[32];
  const float* b_out  = (const float*)d_in[33];
  const float* ln_cg  = (const float*)d_in[34];
  const float* ln_cb  = (const float*)d_in[35];
  const float* w1     = (const float*)d_in[36];
  const float* b1     = (const float*)d_in[37];
  const float* w2     = (const float*)d_in[38];
  const float* b2     = (const float*)d_in[39];
  const float* ln3g   = (const float*)d_in[40];
  const float* ln3b   = (const float*)d_in[41];

  float* out = (float*)d_out;

  // ---- workspace layout (bump allocator, 256B aligned) ----
  char* p = (char*)d_ws;
  auto alloc = [&](size_t bytes) {
    char* r = p; p += (bytes + 255) & ~(size_t)255; return r;
  };
  const size_t MCf = (size_t)M_ROWS * CDIM * 4;    // f32 activation
  float* S[8];
  for (int i = 0; i < 8; i++) S[i] = (float*)alloc(MCf);
  u16* AB0  = (u16*)alloc((size_t)M_ROWS * CDIM * 2);
  u16* AB1  = (u16*)alloc((size_t)M_ROWS * CDIM * 2);
  u16* BB   = (u16*)alloc((size_t)M_ROWS * 1024 * 2);
  u16* SRCB = (u16*)alloc((size_t)SRC_PAD * CDIM * 2);
  u16* VB   = (u16*)alloc((size_t)SRC_PAD * CDIM * 2);
  u16* wqkv_i_b = (u16*)alloc(196608 * 2);
  u16* wo_i_b   = (u16*)alloc(65536 * 2);
  u16* mfw_b    = (u16*)alloc(65536 * 2);
  u16* wqkv_e_b = (u16*)alloc(196608 * 2);
  u16* wo_e_b   = (u16*)alloc(65536 * 2);
  u16* w_off_b  = (u16*)alloc(65536 * 2);
  u16* w_attn_b = (u16*)alloc(32768 * 2);
  u16* w_val_b  = (u16*)alloc(65536 * 2);
  u16* w_out_b  = (u16*)alloc(65536 * 2);
  u16* w1_b     = (u16*)alloc(262144 * 2);
  u16* w2_b     = (u16*)alloc(262144 * 2);
  u16* wc_b     = (u16*)alloc(589824 * 2);
  float* convScale = (float*)alloc(256 * 4);
  float* convShift = (float*)alloc(256 * 4);
  const size_t needed = (size_t)(p - (char*)d_ws);
  if (ws_size < needed) {
    fprintf(stderr, "kernel_launch: workspace too small (%zu < %zu)\n",
            (size_t)ws_size, needed);
    return;
  }

  dim3 blk(256);
  auto cvt = [&](const float* in, u16* ob, int nelem) {
    int n8 = nelem / 8;
    k_f2b8<<<dim3((n8 + 255) / 256), blk, 0, stream>>>(
        (const float4*)in, (short8v*)ob, n8);
  };
  auto gemm = [&](const u16* A, const u16* W, const float* bias,
                  float* Cf, u16* Cb, int M, int N, int K, int relu) {
    gemm_bf16<0><<<dim3(N / 128, M / 128), blk, 0, stream>>>(
        A, W, bias, nullptr, Cf, Cb, M, N, K, relu);
  };

  const int n4 = M_ROWS * CDIM / 4;
  dim3 gadd((n4 + 255) / 256);

  // ---- weight preprocessing (same work every call; graph-safe) ----
  cvt(wqkv_i, wqkv_i_b, 196608);
  cvt(wo_i,   wo_i_b,   65536);
  cvt(mfw,    mfw_b,    65536);
  cvt(wqkv_e, wqkv_e_b, 196608);
  cvt(wo_e,   wo_e_b,   65536);
  cvt(w_off,  w_off_b,  65536);
  cvt(w_attn, w_attn_b, 32768);
  cvt(w_val,  w_val_b,  65536);
  cvt(w_out,  w_out_b,  65536);
  cvt(w1,     w1_b,     262144);
  cvt(w2,     w2_b,     262144);
  k_convw<<<256, blk, 0, stream>>>(conv_w, wc_b);
  k_bnfold<<<1, blk, 0, stream>>>(conv_b, bn_g, bn_b, bn_m, bn_v,
                                  convScale, convShift);
  {
    int n8r = SRC_ROWS * CDIM / 8, n8t = SRC_PAD * CDIM / 8;
    k_src2b<<<dim3((n8t + 255) / 256), blk, 0, stream>>>(
        (const float4*)src, (short8v*)SRCB, n8r, n8t);
  }

  // ---- EFSA intra branch ----
  k_add4<<<gadd, blk, 0, stream>>>((const float4*)tgt, (const float4*)qpos,
                                   (float4*)S[0], n4);            // qk
  cvt(S[0], AB0, M_ROWS * CDIM);
  cvt(tgt,  AB1, M_ROWS * CDIM);
  gemm(AB0, wqkv_i_b,          bqkv_i,       S[1], nullptr, M_ROWS, 256, 256, 0); // qp
  gemm(AB0, wqkv_i_b + 65536,  bqkv_i + 256, S[2], nullptr, M_ROWS, 256, 256, 0); // kp
  gemm(AB1, wqkv_i_b + 131072, bqkv_i + 512, S[3], nullptr, M_ROWS, 256, 256, 0); // vp
  k_attn_intra<<<800 * 8, blk, 0, stream>>>(S[1], S[2], S[3], S[4]);
  cvt(S[4], AB1, M_ROWS * CDIM);
  gemm(AB1, wo_i_b, bo_i, S[5], nullptr, M_ROWS, 256, 256, 0);    // t_attn
  gemm_bf16<1><<<dim3(2, 100), blk, 0, stream>>>(                 // conv+BN+ReLU
      AB0, wc_b, convShift, convScale, S[6], nullptr, M_ROWS, 256, 2304, 1);
  k_ln<<<M_ROWS / 4, blk, 0, stream>>>(S[5], S[6], tgt, ln_ig, ln_ib, S[7], 0); // tgt1
  cvt(S[7], AB0, M_ROWS * CDIM);
  gemm(AB0, mfw_b, mfb, S[1], nullptr, M_ROWS, 256, 256, 0);      // fuse tmp
  k_ln<<<M_ROWS / 4, blk, 0, stream>>>(S[1], nullptr, S[7], ln_fg, ln_fb, S[0], 0); // tgt2

  // ---- inter attention ----
  k_transpose<<<M_ROWS, blk, 0, stream>>>(S[0], S[2]);            // ti (f32)
  cvt(S[2], AB0, M_ROWS * CDIM);
  gemm(AB0, wqkv_e_b,          bqkv_e,       S[3], nullptr, M_ROWS, 256, 256, 0);
  gemm(AB0, wqkv_e_b + 65536,  bqkv_e + 256, S[4], nullptr, M_ROWS, 256, 256, 0);
  gemm(AB0, wqkv_e_b + 131072, bqkv_e + 512, S[5], nullptr, M_ROWS, 256, 256, 0);
  k_attn_inter<<<128 * 8, blk, 0, stream>>>(S[3], S[4], S[5], S[6]);
  cvt(S[6], AB1, M_ROWS * CDIM);
  gemm(AB1, wo_e_b, bo_e, S[1], nullptr, M_ROWS, 256, 256, 0);    // t2
  k_ln<<<M_ROWS / 4, blk, 0, stream>>>(S[2], S[1], nullptr, ln_eg, ln_eb, S[7], 1); // tgt_inter

  // ---- deformable cross attention ----
  k_add4<<<gadd, blk, 0, stream>>>((const float4*)S[7], (const float4*)qpos,
                                   (float4*)S[0], n4);            // q_cross
  cvt(S[0], AB0, M_ROWS * CDIM);
  gemm(SRCB, w_val_b, b_val, nullptr, VB, SRC_PAD, 256, 256, 0);  // value (bf16 out)
  gemm(AB0, w_off_b,  b_off,  S[1], nullptr, M_ROWS, 256, 256, 0); // off
  gemm(AB0, w_attn_b, b_attn, S[2], nullptr, M_ROWS, 128, 256, 0); // aw logits
  k_msda<<<M_ROWS, blk, 0, stream>>>(S[1], S[2], ref, VB, S[3]);  // sampled
  cvt(S[3], AB1, M_ROWS * CDIM);
  gemm(AB1, w_out_b, b_out, S[4], nullptr, M_ROWS, 256, 256, 0);  // t2c
  k_ln<<<M_ROWS / 4, blk, 0, stream>>>(S[7], S[4], nullptr, ln_cg, ln_cb, S[0], 0); // tgt3

  // ---- FFN ----
  cvt(S[0], AB0, M_ROWS * CDIM);
  gemm(AB0, w1_b, b1, nullptr, BB, M_ROWS, 1024, 256, 1);         // relu(h) bf16
  gemm(BB, w2_b, b2, S[1], nullptr, M_ROWS, 256, 1024, 0);        // t2f
  k_ln<<<M_ROWS / 4, blk, 0, stream>>>(S[0], S[1], nullptr, ln3g, ln3b, out, 0); // output
}

// Round 3
// 823.980 us; speedup vs baseline: 2.2651x; 1.2137x over previous
//
#include <hip/hip_runtime.h>
#include <cstdio>
#include <cstddef>

// ---------------------------------------------------------------------------
// DeformableTransformerDecoderLayer — round 2: fused dataflow (bf16 everywhere),
// msda 4-ch/thread, single weight-convert pass, LN with transpose/qpos folded.
// ---------------------------------------------------------------------------

constexpr int CDIM     = 256;
constexpr int M_ROWS   = 12800;        // bs*nq*npts
constexpr int SRC_ROWS = 8 * 19947;    // 159576
constexpr int SRC_PAD  = 159616;       // 1247*128
constexpr float LN_EPS = 1e-5f;
constexpr float SCALE_HD = 0.17677669529663687f; // 32^-0.5

typedef unsigned short u16;
typedef __attribute__((ext_vector_type(8))) short short8v;
typedef __attribute__((ext_vector_type(4))) float f32x4;

__device__ __forceinline__ u16 f2b(float f) {
  unsigned u = __float_as_uint(f);
  unsigned r = (u + 0x7fffu + ((u >> 16) & 1u)) >> 16;
  return (u16)r;
}
__device__ __forceinline__ float b2f(u16 h) {
  return __uint_as_float(((unsigned)h) << 16);
}
__device__ __forceinline__ short8v pack8(float4 x, float4 y) {
  short8v r;
  r[0] = (short)f2b(x.x); r[1] = (short)f2b(x.y);
  r[2] = (short)f2b(x.z); r[3] = (short)f2b(x.w);
  r[4] = (short)f2b(y.x); r[5] = (short)f2b(y.y);
  r[6] = (short)f2b(y.z); r[7] = (short)f2b(y.w);
  return r;
}

// ---------------- qk = bf16(tgt+qpos), tgtb = bf16(tgt) -------------------
__global__ __launch_bounds__(256) void k_qk(const float4* __restrict__ tgt,
    const float4* __restrict__ qpos, short8v* __restrict__ qkb,
    short8v* __restrict__ tgtb, int n8)
{
  int i = blockIdx.x * 256 + threadIdx.x;
  if (i >= n8) return;
  float4 x = tgt[2 * i], y = tgt[2 * i + 1];
  float4 px = qpos[2 * i], py = qpos[2 * i + 1];
  tgtb[i] = pack8(x, y);
  float4 sx = make_float4(x.x + px.x, x.y + px.y, x.z + px.z, x.w + px.w);
  float4 sy = make_float4(y.x + py.x, y.y + py.y, y.z + py.z, y.w + py.w);
  qkb[i] = pack8(sx, sy);
}

// ---------------- all weight converts in one pass -------------------------
__global__ __launch_bounds__(256) void k_wcvt(
    const float* __restrict__ s0, const float* __restrict__ s1,
    const float* __restrict__ s2, const float* __restrict__ s3,
    const float* __restrict__ s4, const float* __restrict__ s5,
    const float* __restrict__ s6, const float* __restrict__ s7,
    const float* __restrict__ s8, const float* __restrict__ s9,
    const float* __restrict__ s10, short8v* __restrict__ dst)
{
  int i = blockIdx.x * 256 + threadIdx.x;
  if (i >= 167936) return;
  int e = i * 8;
  const float* src; int base;
  if      (e < 196608)  { src = s0;  base = 0; }
  else if (e < 262144)  { src = s1;  base = 196608; }
  else if (e < 327680)  { src = s2;  base = 262144; }
  else if (e < 524288)  { src = s3;  base = 327680; }
  else if (e < 589824)  { src = s4;  base = 524288; }
  else if (e < 655360)  { src = s5;  base = 589824; }
  else if (e < 720896)  { src = s6;  base = 655360; }
  else if (e < 983040)  { src = s7;  base = 720896; }
  else if (e < 1245184) { src = s8;  base = 983040; }
  else if (e < 1310720) { src = s9;  base = 1245184; }
  else                  { src = s10; base = 1310720; }
  const float4* sp = (const float4*)(src + (e - base));
  dst[i] = pack8(sp[0], sp[1]);
}

// src convert with zero-padding to SRC_PAD rows
__global__ __launch_bounds__(256) void k_src2b(const float4* __restrict__ in,
    short8v* __restrict__ out, int n8_real, int n8_total)
{
  int i = blockIdx.x * 256 + threadIdx.x;
  if (i >= n8_total) return;
  short8v r;
  if (i >= n8_real) {
#pragma unroll
    for (int j = 0; j < 8; j++) r[j] = 0;
  } else {
    r = pack8(in[2 * i], in[2 * i + 1]);
  }
  out[i] = r;
}

// conv weight reorder: Wc[n][j*256+ci] = conv_w[n][ci][j], bf16
__global__ __launch_bounds__(256) void k_convw(const float* __restrict__ cw,
    u16* __restrict__ wc)
{
  int n = blockIdx.x, ci = threadIdx.x;
  const float* s = cw + (size_t)n * 2304 + (size_t)ci * 9;
#pragma unroll
  for (int j = 0; j < 9; j++)
    wc[(size_t)n * 2304 + j * 256 + ci] = f2b(s[j]);
}

// fold conv bias + BN into scale/shift; concat b_off|b_attn into bcat
__global__ void k_bnfold(const float* __restrict__ cb, const float* __restrict__ g,
    const float* __restrict__ b, const float* __restrict__ m,
    const float* __restrict__ v, const float* __restrict__ boff,
    const float* __restrict__ battn, float* __restrict__ scale,
    float* __restrict__ shift, float* __restrict__ bcat)
{
  int c = threadIdx.x;
  if (c < 256) {
    float s = g[c] * rsqrtf(v[c] + LN_EPS);
    scale[c] = s;
    shift[c] = (cb[c] - m[c]) * s + b[c];
    bcat[c] = boff[c];
  } else {
    bcat[c] = battn[c - 256];
  }
}

// ---------------- bf16 MFMA GEMM (m97 structure) --------------------------
// C[m,n] = sum_k A[m,k]*W[n,k]; 128x128 tile, BK=32, 4 waves.
template<int CONV>
__global__ __launch_bounds__(256) void gemm_bf16(
    const u16* __restrict__ A, const u16* __restrict__ W,
    const float* __restrict__ bias, const float* __restrict__ scale,
    float* __restrict__ Cf, u16* __restrict__ Cb,
    int M, int N, int K, int relu)
{
  __shared__ u16 As[4096];
  __shared__ u16 Bs[4096];
  const int tid = threadIdx.x;
  const int w = tid >> 6, l = tid & 63;
  const int m0 = blockIdx.y * 128, n0 = blockIdx.x * 128;
  const int wr = w >> 1, wc = w & 1;
  const int colA = (l & 3) << 3;
  const int rowBase = (w << 4) + (l >> 2);
  const int lr = l & 15, lk = (l >> 4) << 3;
  f32x4 acc[4][4] = {};

  for (int k0 = 0; k0 < K; k0 += 32) {
#pragma unroll
    for (int i = 0; i < 2; i++) {
      const int row = rowBase + i * 64;
      const u16* ga;
      if (CONV) {
        const int m = m0 + row;
        const int bp = m >> 4, lp = m & 15;
        const int j = k0 >> 8;
        const int sl = (lp + j + 12) & 15;
        ga = A + (((size_t)(bp << 4) + sl) << 8) + (k0 & 255) + colA;
      } else {
        ga = A + (size_t)(m0 + row) * K + k0 + colA;
      }
      __builtin_amdgcn_global_load_lds(
          (const __attribute__((address_space(1))) void*)ga,
          (__attribute__((address_space(3))) void*)&As[(i << 11) + (w << 9)],
          16, 0, 0);
      const u16* gb = W + (size_t)(n0 + row) * K + k0 + colA;
      __builtin_amdgcn_global_load_lds(
          (const __attribute__((address_space(1))) void*)gb,
          (__attribute__((address_space(3))) void*)&Bs[(i << 11) + (w << 9)],
          16, 0, 0);
    }
    __syncthreads();
    short8v a[4], b[4];
#pragma unroll
    for (int t = 0; t < 4; t++) {
      a[t] = *(const short8v*)&As[((wr << 6) + (t << 4) + lr) * 32 + lk];
      b[t] = *(const short8v*)&Bs[((wc << 6) + (t << 4) + lr) * 32 + lk];
    }
#pragma unroll
    for (int mi = 0; mi < 4; mi++)
#pragma unroll
      for (int ni = 0; ni < 4; ni++)
        acc[mi][ni] = __builtin_amdgcn_mfma_f32_16x16x32_bf16(
            a[mi], b[ni], acc[mi][ni], 0, 0, 0);
    __syncthreads();
  }

  const int lq = l >> 4;
#pragma unroll
  for (int ni = 0; ni < 4; ni++) {
    const int n = n0 + (wc << 6) + (ni << 4) + lr;
    const float bs = bias ? bias[n] : 0.f;
    const float sc = scale ? scale[n] : 1.f;
#pragma unroll
    for (int mi = 0; mi < 4; mi++) {
#pragma unroll
      for (int j = 0; j < 4; j++) {
        const int m = m0 + (wr << 6) + (mi << 4) + (lq << 2) + j;
        float v = acc[mi][ni][j] * sc + bs;
        if (relu) v = fmaxf(v, 0.f);
        if (Cb) Cb[(size_t)m * N + n] = f2b(v);
        else    Cf[(size_t)m * N + n] = v;
      }
    }
  }
}

// ---------------- intra attention (bf16 in/out): 800 seqs of L=16 ---------
// qk: [M][512] (q cols 0..255, k cols 256..511); vp: [M][256]; out bf16 [M][256]
__global__ __launch_bounds__(256) void k_attn_intra(
    const u16* __restrict__ qk, const u16* __restrict__ vp,
    u16* __restrict__ o)
{
  const int blk = blockIdx.x;
  const int bp = blk >> 3;
  const int h = blk & 7;
  __shared__ float qs[16][32], ks[16][32], vs[16][32];
  __shared__ float ps[16][17];
  const int t = threadIdx.x;
  for (int e = t; e < 512; e += 256) {
    int l = e >> 5, d = e & 31;
    size_t r = (size_t)(bp * 16 + l);
    qs[l][d] = b2f(qk[r * 512 + h * 32 + d]);
    ks[l][d] = b2f(qk[r * 512 + 256 + h * 32 + d]);
    vs[l][d] = b2f(vp[r * 256 + h * 32 + d]);
  }
  __syncthreads();
  {
    int i = t >> 4, j = t & 15;
    float s = 0.f;
#pragma unroll
    for (int d = 0; d < 32; d++) s += qs[i][d] * ks[j][d];
    ps[i][j] = s * SCALE_HD;
  }
  __syncthreads();
  if (t < 16) {
    float m = -1e30f;
#pragma unroll
    for (int j = 0; j < 16; j++) m = fmaxf(m, ps[t][j]);
    float sum = 0.f;
#pragma unroll
    for (int j = 0; j < 16; j++) { float e = __expf(ps[t][j] - m); ps[t][j] = e; sum += e; }
    float inv = 1.f / sum;
#pragma unroll
    for (int j = 0; j < 16; j++) ps[t][j] *= inv;
  }
  __syncthreads();
  for (int e = t; e < 512; e += 256) {
    int i = e >> 5, d = e & 31;
    float acc = 0.f;
#pragma unroll
    for (int j = 0; j < 16; j++) acc += ps[i][j] * vs[j][d];
    o[((size_t)(bp * 16 + i)) * 256 + h * 32 + d] = f2b(acc);
  }
}

// ---------------- inter attention (bf16 in/out): 128 seqs of L=100 --------
// qkv: [M][768] (q 0, k 256, v 512); out bf16 [M][256]
__global__ __launch_bounds__(256) void k_attn_inter(
    const u16* __restrict__ qkv, u16* __restrict__ o)
{
  const int blk = blockIdx.x;
  const int bb = blk >> 3;
  const int h = blk & 7;
  __shared__ float ks[100][32], vs[100][32];
  const int t = threadIdx.x;
  for (int e = t; e < 3200; e += 256) {
    int r = e >> 5, d = e & 31;
    size_t idx = ((size_t)(bb * 100 + r)) * 768 + h * 32 + d;
    ks[r][d] = b2f(qkv[idx + 256]);
    vs[r][d] = b2f(qkv[idx + 512]);
  }
  __syncthreads();
  if (t < 100) {
    float q[32];
    const size_t rowi = (size_t)(bb * 100 + t);
#pragma unroll
    for (int d = 0; d < 32; d++) q[d] = b2f(qkv[rowi * 768 + h * 32 + d]) * SCALE_HD;
    float m = -1e30f;
    for (int j = 0; j < 100; j++) {
      float s = 0.f;
#pragma unroll
      for (int d = 0; d < 32; d++) s += q[d] * ks[j][d];
      m = fmaxf(m, s);
    }
    float acc[32];
#pragma unroll
    for (int d = 0; d < 32; d++) acc[d] = 0.f;
    float sum = 0.f;
    for (int j = 0; j < 100; j++) {
      float s = 0.f;
#pragma unroll
      for (int d = 0; d < 32; d++) s += q[d] * ks[j][d];
      float e = __expf(s - m);
      sum += e;
#pragma unroll
      for (int d = 0; d < 32; d++) acc[d] += e * vs[j][d];
    }
    float inv = 1.f / sum;
#pragma unroll
    for (int d = 0; d < 32; d++)
      o[rowi * 256 + h * 32 + d] = f2b(acc[d] * inv);
  }
}

// ---------------- LayerNorm, dual output, optional remap/qpos -------------
// MAP 0: orow=row; 1: tgt->ti; 2: ti->tgt. res read at row; qadd at orow.
template<int MAP>
__global__ __launch_bounds__(256) void k_ln(
    const float* __restrict__ a, const float* __restrict__ b,
    const float* __restrict__ res, const float* __restrict__ g,
    const float* __restrict__ beta, float* __restrict__ outf,
    u16* __restrict__ outb, const float* __restrict__ qadd)
{
  const int row = blockIdx.x * 4 + (threadIdx.x >> 6);
  const int lane = threadIdx.x & 63;
  float4 x = ((const float4*)(a + (size_t)row * CDIM))[lane];
  if (b) {
    float4 y = ((const float4*)(b + (size_t)row * CDIM))[lane];
    x.x += y.x; x.y += y.y; x.z += y.z; x.w += y.w;
  }
  float s = x.x + x.y + x.z + x.w;
#pragma unroll
  for (int o = 32; o; o >>= 1) s += __shfl_xor(s, o);
  const float mean = s * (1.f / 256.f);
  float dx = x.x - mean, dy = x.y - mean, dz = x.z - mean, dw = x.w - mean;
  float v = dx * dx + dy * dy + dz * dz + dw * dw;
#pragma unroll
  for (int o = 32; o; o >>= 1) v += __shfl_xor(v, o);
  const float rstd = rsqrtf(v * (1.f / 256.f) + LN_EPS);
  int orow = row;
  if (MAP == 1) {
    int bb = row / 1600, rem = row - bb * 1600;
    int q = rem >> 4, p = rem & 15;
    orow = (bb * 16 + p) * 100 + q;
  } else if (MAP == 2) {
    int bb = row / 1600, rem = row - bb * 1600;
    int p = rem / 100, q = rem - p * 100;
    orow = (bb * 100 + q) * 16 + p;
  }
  const float4 gv = ((const float4*)g)[lane];
  const float4 bv = ((const float4*)beta)[lane];
  float4 r;
  r.x = dx * rstd * gv.x + bv.x;
  r.y = dy * rstd * gv.y + bv.y;
  r.z = dz * rstd * gv.z + bv.z;
  r.w = dw * rstd * gv.w + bv.w;
  if (res) {
    float4 rr = ((const float4*)(res + (size_t)row * CDIM))[lane];
    r.x += rr.x; r.y += rr.y; r.z += rr.z; r.w += rr.w;
  }
  if (outf) ((float4*)(outf + (size_t)orow * CDIM))[lane] = r;
  if (outb) {
    float4 t = r;
    if (qadd) {
      float4 qq = ((const float4*)(qadd + (size_t)orow * CDIM))[lane];
      t.x += qq.x; t.y += qq.y; t.z += qq.z; t.w += qq.w;
    }
    ushort4 o4;
    o4.x = f2b(t.x); o4.y = f2b(t.y); o4.z = f2b(t.z); o4.w = f2b(t.w);
    *(ushort4*)(outb + (size_t)orow * CDIM + lane * 4) = o4;
  }
}

// ---------------- MSDA: 4 channels/thread, bf16 gather/out ----------------
// oa: [M][384] (off 0..255, aw-logits 256..383); out bf16 [M][256]
__global__ __launch_bounds__(256) void k_msda(
    const float* __restrict__ oa, const float* __restrict__ ref,
    const u16* __restrict__ value, u16* __restrict__ outb)
{
  const int row = blockIdx.x * 4 + (threadIdx.x >> 6);
  const int t = threadIdx.x & 63;
  const int h = t >> 3, dg = (t & 7) << 2;   // 4 channels: h*32+dg..+3
  const int b = row / 1600;
  const int q = (row - b * 1600) >> 4;
  const float* awp = oa + (size_t)row * 384 + 256 + h * 16;
  float lg[16];
  float mx = -1e30f;
#pragma unroll
  for (int s = 0; s < 16; s++) { lg[s] = awp[s]; mx = fmaxf(mx, lg[s]); }
  float sum = 0.f;
#pragma unroll
  for (int s = 0; s < 16; s++) { lg[s] = __expf(lg[s] - mx); sum += lg[s]; }
  const float inv = 1.f / sum;
  const float* offp = oa + (size_t)row * 384 + h * 32;
  const int Hs[4] = {100, 50, 25, 13};
  const int Ws[4] = {150, 75, 38, 19};
  const int LS[4] = {0, 15000, 18750, 19700};
  float a0 = 0.f, a1 = 0.f, a2 = 0.f, a3 = 0.f;
#pragma unroll
  for (int l = 0; l < 4; l++) {
    const int Wi = Ws[l], Hi = Hs[l];
    const float rxW = ref[(((size_t)b * 100 + q) * 4 + l) * 2 + 0] * (float)Wi - 0.5f;
    const float ryH = ref[(((size_t)b * 100 + q) * 4 + l) * 2 + 1] * (float)Hi - 0.5f;
    const u16* vb = value + ((size_t)b * 19947 + LS[l]) * 256 + h * 32 + dg;
#pragma unroll
    for (int p = 0; p < 4; p++) {
      const int s = l * 4 + p;
      const float x = rxW + offp[2 * s];
      const float y = ryH + offp[2 * s + 1];
      const float x0f = floorf(x), y0f = floorf(y);
      const float lx = x - x0f, ly = y - y0f;
      const int x0 = (int)x0f, y0 = (int)y0f;
      const int x1 = x0 + 1, y1 = y0 + 1;
      const float vx0 = (x0 >= 0 && x0 < Wi) ? 1.f : 0.f;
      const float vx1 = (x1 >= 0 && x1 < Wi) ? 1.f : 0.f;
      const float vy0 = (y0 >= 0 && y0 < Hi) ? 1.f : 0.f;
      const float vy1 = (y1 >= 0 && y1 < Hi) ? 1.f : 0.f;
      const int xc0 = min(max(x0, 0), Wi - 1), xc1 = min(max(x1, 0), Wi - 1);
      const int yc0 = min(max(y0, 0), Hi - 1), yc1 = min(max(y1, 0), Hi - 1);
      const float wgt = lg[s] * inv;
      const float w00 = (1.f - lx) * (1.f - ly) * vx0 * vy0 * wgt;
      const float w01 = lx * (1.f - ly) * vx1 * vy0 * wgt;
      const float w10 = (1.f - lx) * ly * vx0 * vy1 * wgt;
      const float w11 = lx * ly * vx1 * vy1 * wgt;
      const ushort4 c00 = *(const ushort4*)(vb + (size_t)(yc0 * Wi + xc0) * 256);
      const ushort4 c01 = *(const ushort4*)(vb + (size_t)(yc0 * Wi + xc1) * 256);
      const ushort4 c10 = *(const ushort4*)(vb + (size_t)(yc1 * Wi + xc0) * 256);
      const ushort4 c11 = *(const ushort4*)(vb + (size_t)(yc1 * Wi + xc1) * 256);
      a0 += w00 * b2f(c00.x) + w01 * b2f(c01.x) + w10 * b2f(c10.x) + w11 * b2f(c11.x);
      a1 += w00 * b2f(c00.y) + w01 * b2f(c01.y) + w10 * b2f(c10.y) + w11 * b2f(c11.y);
      a2 += w00 * b2f(c00.z) + w01 * b2f(c01.z) + w10 * b2f(c10.z) + w11 * b2f(c11.z);
      a3 += w00 * b2f(c00.w) + w01 * b2f(c01.w) + w10 * b2f(c10.w) + w11 * b2f(c11.w);
    }
  }
  ushort4 o4;
  o4.x = f2b(a0); o4.y = f2b(a1); o4.z = f2b(a2); o4.w = f2b(a3);
  *(ushort4*)(outb + (size_t)row * 256 + h * 32 + dg) = o4;
}

// ---------------------------------------------------------------------------
extern "C" void kernel_launch(void* const* d_in, const int* in_sizes, int n_in,
                              void* d_out, int out_size, void* d_ws, size_t ws_size,
                              hipStream_t stream)
{
  const float* tgt    = (const float*)d_in[0];
  const float* qpos   = (const float*)d_in[1];
  const float* ref    = (const float*)d_in[2];
  const float* src    = (const float*)d_in[3];
  const float* wqkv_i = (const float*)d_in[4];
  const float* bqkv_i = (const float*)d_in[5];
  const float* wo_i   = (const float*)d_in[6];
  const float* bo_i   = (const float*)d_in[7];
  const float* conv_w = (const float*)d_in[8];
  const float* conv_b = (const float*)d_in[9];
  const float* bn_g   = (const float*)d_in[10];
  const float* bn_b   = (const float*)d_in[11];
  const float* bn_m   = (const float*)d_in[12];
  const float* bn_v   = (const float*)d_in[13];
  const float* ln_ig  = (const float*)d_in[14];
  const float* ln_ib  = (const float*)d_in[15];
  const float* mfw    = (const float*)d_in[16];
  const float* mfb    = (const float*)d_in[17];
  const float* ln_fg  = (const float*)d_in[18];
  const float* ln_fb  = (const float*)d_in[19];
  const float* wqkv_e = (const float*)d_in[20];
  const float* bqkv_e = (const float*)d_in[21];
  const float* wo_e   = (const float*)d_in[22];
  const float* bo_e   = (const float*)d_in[23];
  const float* ln_eg  = (const float*)d_in[24];
  const float* ln_eb  = (const float*)d_in[25];
  const float* w_off  = (const float*)d_in[26];
  const float* b_off  = (const float*)d_in[27];
  const float* w_attn = (const float*)d_in[28];
  const float* b_attn = (const float*)d_in[29];
  const float* w_val  = (const float*)d_in[30];
  const float* b_val  = (const float*)d_in[31];
  const float* w_out  = (const float*)d_in[32];
  const float* b_out  = (const float*)d_in[33];
  const float* ln_cg  = (const float*)d_in[34];
  const float* ln_cb  = (const float*)d_in[35];
  const float* w1     = (const float*)d_in[36];
  const float* b1     = (const float*)d_in[37];
  const float* w2     = (const float*)d_in[38];
  const float* b2     = (const float*)d_in[39];
  const float* ln3g   = (const float*)d_in[40];
  const float* ln3b   = (const float*)d_in[41];

  float* out = (float*)d_out;

  // ---- workspace layout ----
  char* p = (char*)d_ws;
  auto alloc = [&](size_t bytes) {
    char* r = p; p += (bytes + 255) & ~(size_t)255; return r;
  };
  const size_t MCf = (size_t)M_ROWS * CDIM * 4;
  const size_t MCb = (size_t)M_ROWS * CDIM * 2;
  float* S0 = (float*)alloc(MCf);
  float* S1 = (float*)alloc(MCf);
  float* S2 = (float*)alloc(MCf);
  float* OA = (float*)alloc((size_t)M_ROWS * 384 * 4);
  u16* X0 = (u16*)alloc(MCb);
  u16* X1 = (u16*)alloc(MCb);
  u16* X2 = (u16*)alloc(MCb);
  u16* X3 = (u16*)alloc(MCb);
  u16* B768 = (u16*)alloc((size_t)M_ROWS * 768 * 2);
  u16* BB   = (u16*)alloc((size_t)M_ROWS * 1024 * 2);
  u16* SRCB = (u16*)alloc((size_t)SRC_PAD * CDIM * 2);
  u16* VB   = (u16*)alloc((size_t)SRC_PAD * CDIM * 2);
  u16* W_b  = (u16*)alloc(1343488 * 2);
  u16* wc_b = (u16*)alloc(589824 * 2);
  float* convScale = (float*)alloc(256 * 4);
  float* convShift = (float*)alloc(256 * 4);
  float* bcat      = (float*)alloc(384 * 4);
  const size_t needed = (size_t)(p - (char*)d_ws);
  if (ws_size < needed) {
    fprintf(stderr, "kernel_launch: workspace too small (%zu < %zu)\n",
            (size_t)ws_size, needed);
    return;
  }
  // weight aliases into W_b
  u16* wqkv_i_b = W_b + 0;        // q,k at 0; v at 131072
  u16* wo_i_b   = W_b + 196608;
  u16* mfw_b    = W_b + 262144;
  u16* wqkv_e_b = W_b + 327680;
  u16* wo_e_b   = W_b + 524288;
  u16* w_val_b  = W_b + 589824;
  u16* w_out_b  = W_b + 655360;
  u16* w1_b     = W_b + 720896;
  u16* w2_b     = W_b + 983040;
  u16* wcat_b   = W_b + 1245184;  // off(256 rows) | attn(128 rows)

  dim3 blk(256);
  auto gemm = [&](const u16* A, const u16* W, const float* bias,
                  float* Cf, u16* Cb, int M, int N, int K, int relu) {
    gemm_bf16<0><<<dim3(N / 128, M / 128), blk, 0, stream>>>(
        A, W, bias, nullptr, Cf, Cb, M, N, K, relu);
  };

  // ---- preprocessing (4 dispatches) ----
  k_wcvt<<<dim3((167936 + 255) / 256), blk, 0, stream>>>(
      wqkv_i, wo_i, mfw, wqkv_e, wo_e, w_val, w_out, w1, w2, w_off, w_attn,
      (short8v*)W_b);
  k_convw<<<256, blk, 0, stream>>>(conv_w, wc_b);
  k_bnfold<<<1, dim3(384), 0, stream>>>(conv_b, bn_g, bn_b, bn_m, bn_v,
                                        b_off, b_attn, convScale, convShift, bcat);
  {
    int n8r = SRC_ROWS * CDIM / 8, n8t = SRC_PAD * CDIM / 8;
    k_src2b<<<dim3((n8t + 255) / 256), blk, 0, stream>>>(
        (const float4*)src, (short8v*)SRCB, n8r, n8t);
  }

  const int n8 = M_ROWS * CDIM / 8;

  // ---- EFSA intra branch ----
  k_qk<<<dim3((n8 + 255) / 256), blk, 0, stream>>>(
      (const float4*)tgt, (const float4*)qpos, (short8v*)X0, (short8v*)X1, n8); // X0=qk_b X1=tgt_b
  gemm(X0, wqkv_i_b, bqkv_i, nullptr, B768, M_ROWS, 512, 256, 0);      // Q|K (ld 512)
  gemm(X1, wqkv_i_b + 131072, bqkv_i + 512, nullptr, X2, M_ROWS, 256, 256, 0); // V
  k_attn_intra<<<800 * 8, blk, 0, stream>>>(B768, X2, X3);             // X3=attn out
  gemm(X3, wo_i_b, bo_i, S0, nullptr, M_ROWS, 256, 256, 0);            // t_attn f32
  gemm_bf16<1><<<dim3(2, 100), blk, 0, stream>>>(                      // conv+BN+ReLU
      X0, wc_b, convShift, convScale, S1, nullptr, M_ROWS, 256, 2304, 1);
  k_ln<0><<<M_ROWS / 4, blk, 0, stream>>>(S0, S1, tgt, ln_ig, ln_ib,
                                          S2, X1, nullptr);            // tgt1: S2 + X1
  gemm(X1, mfw_b, mfb, S0, nullptr, M_ROWS, 256, 256, 0);              // fuse tmp
  k_ln<1><<<M_ROWS / 4, blk, 0, stream>>>(S0, nullptr, S2, ln_fg, ln_fb,
                                          S1, X2, nullptr);            // tgt2 (ti layout): S1 + X2

  // ---- inter attention ----
  gemm(X2, wqkv_e_b, bqkv_e, nullptr, B768, M_ROWS, 768, 256, 0);      // QKV inter
  k_attn_inter<<<128 * 8, blk, 0, stream>>>(B768, X3);                 // X3=attn out (ti rows)
  gemm(X3, wo_e_b, bo_e, S0, nullptr, M_ROWS, 256, 256, 0);            // t2 (ti rows)
  k_ln<2><<<M_ROWS / 4, blk, 0, stream>>>(S1, S0, nullptr, ln_eg, ln_eb,
                                          S2, X0, qpos);               // tgt_inter: S2; X0=q_cross_b

  // ---- deformable cross attention ----
  gemm(SRCB, w_val_b, b_val, nullptr, VB, SRC_PAD, 256, 256, 0);       // value bf16
  gemm(X0, wcat_b, bcat, OA, nullptr, M_ROWS, 384, 256, 0);            // off|aw logits
  k_msda<<<M_ROWS / 4, blk, 0, stream>>>(OA, ref, VB, X1);             // X1=sampled bf16
  gemm(X1, w_out_b, b_out, S0, nullptr, M_ROWS, 256, 256, 0);          // t2c
  k_ln<0><<<M_ROWS / 4, blk, 0, stream>>>(S2, S0, nullptr, ln_cg, ln_cb,
                                          S1, X2, nullptr);            // tgt3: S1 + X2

  // ---- FFN ----
  gemm(X2, w1_b, b1, nullptr, BB, M_ROWS, 1024, 256, 1);               // relu(h) bf16
  gemm(BB, w2_b, b2, S0, nullptr, M_ROWS, 256, 1024, 0);               // t2f
  k_ln<0><<<M_ROWS / 4, blk, 0, stream>>>(S1, S0, nullptr, ln3g, ln3b,
                                          out, nullptr, nullptr);      // output
}

// Round 4
// 769.566 us; speedup vs baseline: 2.4252x; 1.0707x over previous
//
#include <hip/hip_runtime.h>
#include <cstdio>
#include <cstddef>

// ---------------------------------------------------------------------------
// DeformableTransformerDecoderLayer — round 3: 64x64-tile GEMM for the small
// latency-bound GEMMs (800+ blocks instead of 200), 128x128 kept for the
// throughput-bound value GEMM. Rest of round-2 fused dataflow unchanged.
// ---------------------------------------------------------------------------

constexpr int CDIM     = 256;
constexpr int M_ROWS   = 12800;        // bs*nq*npts
constexpr int SRC_ROWS = 8 * 19947;    // 159576
constexpr int SRC_PAD  = 159616;       // 1247*128
constexpr float LN_EPS = 1e-5f;
constexpr float SCALE_HD = 0.17677669529663687f; // 32^-0.5

typedef unsigned short u16;
typedef __attribute__((ext_vector_type(8))) short short8v;
typedef __attribute__((ext_vector_type(4))) float f32x4;

__device__ __forceinline__ u16 f2b(float f) {
  unsigned u = __float_as_uint(f);
  unsigned r = (u + 0x7fffu + ((u >> 16) & 1u)) >> 16;
  return (u16)r;
}
__device__ __forceinline__ float b2f(u16 h) {
  return __uint_as_float(((unsigned)h) << 16);
}
__device__ __forceinline__ short8v pack8(float4 x, float4 y) {
  short8v r;
  r[0] = (short)f2b(x.x); r[1] = (short)f2b(x.y);
  r[2] = (short)f2b(x.z); r[3] = (short)f2b(x.w);
  r[4] = (short)f2b(y.x); r[5] = (short)f2b(y.y);
  r[6] = (short)f2b(y.z); r[7] = (short)f2b(y.w);
  return r;
}

// ---------------- qk = bf16(tgt+qpos), tgtb = bf16(tgt) -------------------
__global__ __launch_bounds__(256) void k_qk(const float4* __restrict__ tgt,
    const float4* __restrict__ qpos, short8v* __restrict__ qkb,
    short8v* __restrict__ tgtb, int n8)
{
  int i = blockIdx.x * 256 + threadIdx.x;
  if (i >= n8) return;
  float4 x = tgt[2 * i], y = tgt[2 * i + 1];
  float4 px = qpos[2 * i], py = qpos[2 * i + 1];
  tgtb[i] = pack8(x, y);
  float4 sx = make_float4(x.x + px.x, x.y + px.y, x.z + px.z, x.w + px.w);
  float4 sy = make_float4(y.x + py.x, y.y + py.y, y.z + py.z, y.w + py.w);
  qkb[i] = pack8(sx, sy);
}

// ---------------- all weight converts in one pass -------------------------
__global__ __launch_bounds__(256) void k_wcvt(
    const float* __restrict__ s0, const float* __restrict__ s1,
    const float* __restrict__ s2, const float* __restrict__ s3,
    const float* __restrict__ s4, const float* __restrict__ s5,
    const float* __restrict__ s6, const float* __restrict__ s7,
    const float* __restrict__ s8, const float* __restrict__ s9,
    const float* __restrict__ s10, short8v* __restrict__ dst)
{
  int i = blockIdx.x * 256 + threadIdx.x;
  if (i >= 167936) return;
  int e = i * 8;
  const float* src; int base;
  if      (e < 196608)  { src = s0;  base = 0; }
  else if (e < 262144)  { src = s1;  base = 196608; }
  else if (e < 327680)  { src = s2;  base = 262144; }
  else if (e < 524288)  { src = s3;  base = 327680; }
  else if (e < 589824)  { src = s4;  base = 524288; }
  else if (e < 655360)  { src = s5;  base = 589824; }
  else if (e < 720896)  { src = s6;  base = 655360; }
  else if (e < 983040)  { src = s7;  base = 720896; }
  else if (e < 1245184) { src = s8;  base = 983040; }
  else if (e < 1310720) { src = s9;  base = 1245184; }
  else                  { src = s10; base = 1310720; }
  const float4* sp = (const float4*)(src + (e - base));
  dst[i] = pack8(sp[0], sp[1]);
}

// src convert with zero-padding to SRC_PAD rows
__global__ __launch_bounds__(256) void k_src2b(const float4* __restrict__ in,
    short8v* __restrict__ out, int n8_real, int n8_total)
{
  int i = blockIdx.x * 256 + threadIdx.x;
  if (i >= n8_total) return;
  short8v r;
  if (i >= n8_real) {
#pragma unroll
    for (int j = 0; j < 8; j++) r[j] = 0;
  } else {
    r = pack8(in[2 * i], in[2 * i + 1]);
  }
  out[i] = r;
}

// conv weight reorder: Wc[n][j*256+ci] = conv_w[n][ci][j], bf16
__global__ __launch_bounds__(256) void k_convw(const float* __restrict__ cw,
    u16* __restrict__ wc)
{
  int n = blockIdx.x, ci = threadIdx.x;
  const float* s = cw + (size_t)n * 2304 + (size_t)ci * 9;
#pragma unroll
  for (int j = 0; j < 9; j++)
    wc[(size_t)n * 2304 + j * 256 + ci] = f2b(s[j]);
}

// fold conv bias + BN into scale/shift; concat b_off|b_attn into bcat
__global__ void k_bnfold(const float* __restrict__ cb, const float* __restrict__ g,
    const float* __restrict__ b, const float* __restrict__ m,
    const float* __restrict__ v, const float* __restrict__ boff,
    const float* __restrict__ battn, float* __restrict__ scale,
    float* __restrict__ shift, float* __restrict__ bcat)
{
  int c = threadIdx.x;
  if (c < 256) {
    float s = g[c] * rsqrtf(v[c] + LN_EPS);
    scale[c] = s;
    shift[c] = (cb[c] - m[c]) * s + b[c];
    bcat[c] = boff[c];
  } else {
    bcat[c] = battn[c - 256];
  }
}

// ---------------- 64x64-tile bf16 MFMA GEMM (latency-optimized) -----------
// C[m,n] = sum_k A[m,k]*W[n,k]; BK=32, 4 waves as 2x2 of 32x32 wave-tiles.
// 8 KB LDS; one 16B global_load_lds per thread per tile per K-step.
// CONV=1: A is qk_b [800][16][256]; circular im2col folded into staging.
template<int CONV>
__global__ __launch_bounds__(256) void gemm64(
    const u16* __restrict__ A, const u16* __restrict__ W,
    const float* __restrict__ bias, const float* __restrict__ scale,
    float* __restrict__ Cf, u16* __restrict__ Cb,
    int M, int N, int K, int relu)
{
  __shared__ u16 As[2048];
  __shared__ u16 Bs[2048];
  const int tid = threadIdx.x;
  const int w = tid >> 6, l = tid & 63;
  const int m0 = blockIdx.y * 64, n0 = blockIdx.x * 64;
  const int wr = w >> 1, wc = w & 1;
  const int colA = (l & 3) << 3;            // element offset 0,8,16,24
  const int rowS = (w << 4) + (l >> 2);     // staging row 0..63
  const int lr = l & 15, lk = (l >> 4) << 3;
  f32x4 acc[2][2] = {};

  for (int k0 = 0; k0 < K; k0 += 32) {
    const u16* ga;
    if (CONV) {
      const int m = m0 + rowS;
      const int bp = m >> 4, lp = m & 15;
      const int j = k0 >> 8;
      const int sl = (lp + j + 12) & 15;
      ga = A + (((size_t)(bp << 4) + sl) << 8) + (k0 & 255) + colA;
    } else {
      ga = A + (size_t)(m0 + rowS) * K + k0 + colA;
    }
    __builtin_amdgcn_global_load_lds(
        (const __attribute__((address_space(1))) void*)ga,
        (__attribute__((address_space(3))) void*)&As[w << 9],
        16, 0, 0);
    const u16* gb = W + (size_t)(n0 + rowS) * K + k0 + colA;
    __builtin_amdgcn_global_load_lds(
        (const __attribute__((address_space(1))) void*)gb,
        (__attribute__((address_space(3))) void*)&Bs[w << 9],
        16, 0, 0);
    __syncthreads();
    short8v a[2], b[2];
#pragma unroll
    for (int t = 0; t < 2; t++) {
      a[t] = *(const short8v*)&As[((wr << 5) + (t << 4) + lr) * 32 + lk];
      b[t] = *(const short8v*)&Bs[((wc << 5) + (t << 4) + lr) * 32 + lk];
    }
#pragma unroll
    for (int mi = 0; mi < 2; mi++)
#pragma unroll
      for (int ni = 0; ni < 2; ni++)
        acc[mi][ni] = __builtin_amdgcn_mfma_f32_16x16x32_bf16(
            a[mi], b[ni], acc[mi][ni], 0, 0, 0);
    __syncthreads();
  }

  const int lq = l >> 4;
#pragma unroll
  for (int ni = 0; ni < 2; ni++) {
    const int n = n0 + (wc << 5) + (ni << 4) + lr;
    const float bs = bias ? bias[n] : 0.f;
    const float sc = scale ? scale[n] : 1.f;
#pragma unroll
    for (int mi = 0; mi < 2; mi++) {
#pragma unroll
      for (int j = 0; j < 4; j++) {
        const int m = m0 + (wr << 5) + (mi << 4) + (lq << 2) + j;
        float v = acc[mi][ni][j] * sc + bs;
        if (relu) v = fmaxf(v, 0.f);
        if (Cb) Cb[(size_t)m * N + n] = f2b(v);
        else    Cf[(size_t)m * N + n] = v;
      }
    }
  }
}

// ---------------- 128x128-tile bf16 MFMA GEMM (throughput, value GEMM) ----
__global__ __launch_bounds__(256) void gemm128(
    const u16* __restrict__ A, const u16* __restrict__ W,
    const float* __restrict__ bias,
    float* __restrict__ Cf, u16* __restrict__ Cb,
    int M, int N, int K, int relu)
{
  __shared__ u16 As[4096];
  __shared__ u16 Bs[4096];
  const int tid = threadIdx.x;
  const int w = tid >> 6, l = tid & 63;
  const int m0 = blockIdx.y * 128, n0 = blockIdx.x * 128;
  const int wr = w >> 1, wc = w & 1;
  const int colA = (l & 3) << 3;
  const int rowBase = (w << 4) + (l >> 2);
  const int lr = l & 15, lk = (l >> 4) << 3;
  f32x4 acc[4][4] = {};

  for (int k0 = 0; k0 < K; k0 += 32) {
#pragma unroll
    for (int i = 0; i < 2; i++) {
      const int row = rowBase + i * 64;
      const u16* ga = A + (size_t)(m0 + row) * K + k0 + colA;
      __builtin_amdgcn_global_load_lds(
          (const __attribute__((address_space(1))) void*)ga,
          (__attribute__((address_space(3))) void*)&As[(i << 11) + (w << 9)],
          16, 0, 0);
      const u16* gb = W + (size_t)(n0 + row) * K + k0 + colA;
      __builtin_amdgcn_global_load_lds(
          (const __attribute__((address_space(1))) void*)gb,
          (__attribute__((address_space(3))) void*)&Bs[(i << 11) + (w << 9)],
          16, 0, 0);
    }
    __syncthreads();
    short8v a[4], b[4];
#pragma unroll
    for (int t = 0; t < 4; t++) {
      a[t] = *(const short8v*)&As[((wr << 6) + (t << 4) + lr) * 32 + lk];
      b[t] = *(const short8v*)&Bs[((wc << 6) + (t << 4) + lr) * 32 + lk];
    }
#pragma unroll
    for (int mi = 0; mi < 4; mi++)
#pragma unroll
      for (int ni = 0; ni < 4; ni++)
        acc[mi][ni] = __builtin_amdgcn_mfma_f32_16x16x32_bf16(
            a[mi], b[ni], acc[mi][ni], 0, 0, 0);
    __syncthreads();
  }

  const int lq = l >> 4;
#pragma unroll
  for (int ni = 0; ni < 4; ni++) {
    const int n = n0 + (wc << 6) + (ni << 4) + lr;
    const float bs = bias ? bias[n] : 0.f;
#pragma unroll
    for (int mi = 0; mi < 4; mi++) {
#pragma unroll
      for (int j = 0; j < 4; j++) {
        const int m = m0 + (wr << 6) + (mi << 4) + (lq << 2) + j;
        float v = acc[mi][ni][j] + bs;
        if (relu) v = fmaxf(v, 0.f);
        if (Cb) Cb[(size_t)m * N + n] = f2b(v);
        else    Cf[(size_t)m * N + n] = v;
      }
    }
  }
}

// ---------------- intra attention (bf16 in/out): 800 seqs of L=16 ---------
__global__ __launch_bounds__(256) void k_attn_intra(
    const u16* __restrict__ qk, const u16* __restrict__ vp,
    u16* __restrict__ o)
{
  const int blk = blockIdx.x;
  const int bp = blk >> 3;
  const int h = blk & 7;
  __shared__ float qs[16][32], ks[16][32], vs[16][32];
  __shared__ float ps[16][17];
  const int t = threadIdx.x;
  for (int e = t; e < 512; e += 256) {
    int l = e >> 5, d = e & 31;
    size_t r = (size_t)(bp * 16 + l);
    qs[l][d] = b2f(qk[r * 512 + h * 32 + d]);
    ks[l][d] = b2f(qk[r * 512 + 256 + h * 32 + d]);
    vs[l][d] = b2f(vp[r * 256 + h * 32 + d]);
  }
  __syncthreads();
  {
    int i = t >> 4, j = t & 15;
    float s = 0.f;
#pragma unroll
    for (int d = 0; d < 32; d++) s += qs[i][d] * ks[j][d];
    ps[i][j] = s * SCALE_HD;
  }
  __syncthreads();
  if (t < 16) {
    float m = -1e30f;
#pragma unroll
    for (int j = 0; j < 16; j++) m = fmaxf(m, ps[t][j]);
    float sum = 0.f;
#pragma unroll
    for (int j = 0; j < 16; j++) { float e = __expf(ps[t][j] - m); ps[t][j] = e; sum += e; }
    float inv = 1.f / sum;
#pragma unroll
    for (int j = 0; j < 16; j++) ps[t][j] *= inv;
  }
  __syncthreads();
  for (int e = t; e < 512; e += 256) {
    int i = e >> 5, d = e & 31;
    float acc = 0.f;
#pragma unroll
    for (int j = 0; j < 16; j++) acc += ps[i][j] * vs[j][d];
    o[((size_t)(bp * 16 + i)) * 256 + h * 32 + d] = f2b(acc);
  }
}

// ---------------- inter attention (bf16 in/out): 128 seqs of L=100 --------
__global__ __launch_bounds__(256) void k_attn_inter(
    const u16* __restrict__ qkv, u16* __restrict__ o)
{
  const int blk = blockIdx.x;
  const int bb = blk >> 3;
  const int h = blk & 7;
  __shared__ float ks[100][32], vs[100][32];
  const int t = threadIdx.x;
  for (int e = t; e < 3200; e += 256) {
    int r = e >> 5, d = e & 31;
    size_t idx = ((size_t)(bb * 100 + r)) * 768 + h * 32 + d;
    ks[r][d] = b2f(qkv[idx + 256]);
    vs[r][d] = b2f(qkv[idx + 512]);
  }
  __syncthreads();
  if (t < 100) {
    float q[32];
    const size_t rowi = (size_t)(bb * 100 + t);
#pragma unroll
    for (int d = 0; d < 32; d++) q[d] = b2f(qkv[rowi * 768 + h * 32 + d]) * SCALE_HD;
    float m = -1e30f;
    for (int j = 0; j < 100; j++) {
      float s = 0.f;
#pragma unroll
      for (int d = 0; d < 32; d++) s += q[d] * ks[j][d];
      m = fmaxf(m, s);
    }
    float acc[32];
#pragma unroll
    for (int d = 0; d < 32; d++) acc[d] = 0.f;
    float sum = 0.f;
    for (int j = 0; j < 100; j++) {
      float s = 0.f;
#pragma unroll
      for (int d = 0; d < 32; d++) s += q[d] * ks[j][d];
      float e = __expf(s - m);
      sum += e;
#pragma unroll
      for (int d = 0; d < 32; d++) acc[d] += e * vs[j][d];
    }
    float inv = 1.f / sum;
#pragma unroll
    for (int d = 0; d < 32; d++)
      o[rowi * 256 + h * 32 + d] = f2b(acc[d] * inv);
  }
}

// ---------------- LayerNorm, dual output, optional remap/qpos -------------
template<int MAP>
__global__ __launch_bounds__(256) void k_ln(
    const float* __restrict__ a, const float* __restrict__ b,
    const float* __restrict__ res, const float* __restrict__ g,
    const float* __restrict__ beta, float* __restrict__ outf,
    u16* __restrict__ outb, const float* __restrict__ qadd)
{
  const int row = blockIdx.x * 4 + (threadIdx.x >> 6);
  const int lane = threadIdx.x & 63;
  float4 x = ((const float4*)(a + (size_t)row * CDIM))[lane];
  if (b) {
    float4 y = ((const float4*)(b + (size_t)row * CDIM))[lane];
    x.x += y.x; x.y += y.y; x.z += y.z; x.w += y.w;
  }
  float s = x.x + x.y + x.z + x.w;
#pragma unroll
  for (int o = 32; o; o >>= 1) s += __shfl_xor(s, o);
  const float mean = s * (1.f / 256.f);
  float dx = x.x - mean, dy = x.y - mean, dz = x.z - mean, dw = x.w - mean;
  float v = dx * dx + dy * dy + dz * dz + dw * dw;
#pragma unroll
  for (int o = 32; o; o >>= 1) v += __shfl_xor(v, o);
  const float rstd = rsqrtf(v * (1.f / 256.f) + LN_EPS);
  int orow = row;
  if (MAP == 1) {
    int bb = row / 1600, rem = row - bb * 1600;
    int q = rem >> 4, p = rem & 15;
    orow = (bb * 16 + p) * 100 + q;
  } else if (MAP == 2) {
    int bb = row / 1600, rem = row - bb * 1600;
    int p = rem / 100, q = rem - p * 100;
    orow = (bb * 100 + q) * 16 + p;
  }
  const float4 gv = ((const float4*)g)[lane];
  const float4 bv = ((const float4*)beta)[lane];
  float4 r;
  r.x = dx * rstd * gv.x + bv.x;
  r.y = dy * rstd * gv.y + bv.y;
  r.z = dz * rstd * gv.z + bv.z;
  r.w = dw * rstd * gv.w + bv.w;
  if (res) {
    float4 rr = ((const float4*)(res + (size_t)row * CDIM))[lane];
    r.x += rr.x; r.y += rr.y; r.z += rr.z; r.w += rr.w;
  }
  if (outf) ((float4*)(outf + (size_t)orow * CDIM))[lane] = r;
  if (outb) {
    float4 t = r;
    if (qadd) {
      float4 qq = ((const float4*)(qadd + (size_t)orow * CDIM))[lane];
      t.x += qq.x; t.y += qq.y; t.z += qq.z; t.w += qq.w;
    }
    ushort4 o4;
    o4.x = f2b(t.x); o4.y = f2b(t.y); o4.z = f2b(t.z); o4.w = f2b(t.w);
    *(ushort4*)(outb + (size_t)orow * CDIM + lane * 4) = o4;
  }
}

// ---------------- MSDA: 4 channels/thread, bf16 gather/out ----------------
__global__ __launch_bounds__(256) void k_msda(
    const float* __restrict__ oa, const float* __restrict__ ref,
    const u16* __restrict__ value, u16* __restrict__ outb)
{
  const int row = blockIdx.x * 4 + (threadIdx.x >> 6);
  const int t = threadIdx.x & 63;
  const int h = t >> 3, dg = (t & 7) << 2;
  const int b = row / 1600;
  const int q = (row - b * 1600) >> 4;
  const float* awp = oa + (size_t)row * 384 + 256 + h * 16;
  float lg[16];
  float mx = -1e30f;
#pragma unroll
  for (int s = 0; s < 16; s++) { lg[s] = awp[s]; mx = fmaxf(mx, lg[s]); }
  float sum = 0.f;
#pragma unroll
  for (int s = 0; s < 16; s++) { lg[s] = __expf(lg[s] - mx); sum += lg[s]; }
  const float inv = 1.f / sum;
  const float* offp = oa + (size_t)row * 384 + h * 32;
  const int Hs[4] = {100, 50, 25, 13};
  const int Ws[4] = {150, 75, 38, 19};
  const int LS[4] = {0, 15000, 18750, 19700};
  float a0 = 0.f, a1 = 0.f, a2 = 0.f, a3 = 0.f;
#pragma unroll
  for (int l = 0; l < 4; l++) {
    const int Wi = Ws[l], Hi = Hs[l];
    const float rxW = ref[(((size_t)b * 100 + q) * 4 + l) * 2 + 0] * (float)Wi - 0.5f;
    const float ryH = ref[(((size_t)b * 100 + q) * 4 + l) * 2 + 1] * (float)Hi - 0.5f;
    const u16* vb = value + ((size_t)b * 19947 + LS[l]) * 256 + h * 32 + dg;
#pragma unroll
    for (int p = 0; p < 4; p++) {
      const int s = l * 4 + p;
      const float x = rxW + offp[2 * s];
      const float y = ryH + offp[2 * s + 1];
      const float x0f = floorf(x), y0f = floorf(y);
      const float lx = x - x0f, ly = y - y0f;
      const int x0 = (int)x0f, y0 = (int)y0f;
      const int x1 = x0 + 1, y1 = y0 + 1;
      const float vx0 = (x0 >= 0 && x0 < Wi) ? 1.f : 0.f;
      const float vx1 = (x1 >= 0 && x1 < Wi) ? 1.f : 0.f;
      const float vy0 = (y0 >= 0 && y0 < Hi) ? 1.f : 0.f;
      const float vy1 = (y1 >= 0 && y1 < Hi) ? 1.f : 0.f;
      const int xc0 = min(max(x0, 0), Wi - 1), xc1 = min(max(x1, 0), Wi - 1);
      const int yc0 = min(max(y0, 0), Hi - 1), yc1 = min(max(y1, 0), Hi - 1);
      const float wgt = lg[s] * inv;
      const float w00 = (1.f - lx) * (1.f - ly) * vx0 * vy0 * wgt;
      const float w01 = lx * (1.f - ly) * vx1 * vy0 * wgt;
      const float w10 = (1.f - lx) * ly * vx0 * vy1 * wgt;
      const float w11 = lx * ly * vx1 * vy1 * wgt;
      const ushort4 c00 = *(const ushort4*)(vb + (size_t)(yc0 * Wi + xc0) * 256);
      const ushort4 c01 = *(const ushort4*)(vb + (size_t)(yc0 * Wi + xc1) * 256);
      const ushort4 c10 = *(const ushort4*)(vb + (size_t)(yc1 * Wi + xc0) * 256);
      const ushort4 c11 = *(const ushort4*)(vb + (size_t)(yc1 * Wi + xc1) * 256);
      a0 += w00 * b2f(c00.x) + w01 * b2f(c01.x) + w10 * b2f(c10.x) + w11 * b2f(c11.x);
      a1 += w00 * b2f(c00.y) + w01 * b2f(c01.y) + w10 * b2f(c10.y) + w11 * b2f(c11.y);
      a2 += w00 * b2f(c00.z) + w01 * b2f(c01.z) + w10 * b2f(c10.z) + w11 * b2f(c11.z);
      a3 += w00 * b2f(c00.w) + w01 * b2f(c01.w) + w10 * b2f(c10.w) + w11 * b2f(c11.w);
    }
  }
  ushort4 o4;
  o4.x = f2b(a0); o4.y = f2b(a1); o4.z = f2b(a2); o4.w = f2b(a3);
  *(ushort4*)(outb + (size_t)row * 256 + h * 32 + dg) = o4;
}

// ---------------------------------------------------------------------------
extern "C" void kernel_launch(void* const* d_in, const int* in_sizes, int n_in,
                              void* d_out, int out_size, void* d_ws, size_t ws_size,
                              hipStream_t stream)
{
  const float* tgt    = (const float*)d_in[0];
  const float* qpos   = (const float*)d_in[1];
  const float* ref    = (const float*)d_in[2];
  const float* src    = (const float*)d_in[3];
  const float* wqkv_i = (const float*)d_in[4];
  const float* bqkv_i = (const float*)d_in[5];
  const float* wo_i   = (const float*)d_in[6];
  const float* bo_i   = (const float*)d_in[7];
  const float* conv_w = (const float*)d_in[8];
  const float* conv_b = (const float*)d_in[9];
  const float* bn_g   = (const float*)d_in[10];
  const float* bn_b   = (const float*)d_in[11];
  const float* bn_m   = (const float*)d_in[12];
  const float* bn_v   = (const float*)d_in[13];
  const float* ln_ig  = (const float*)d_in[14];
  const float* ln_ib  = (const float*)d_in[15];
  const float* mfw    = (const float*)d_in[16];
  const float* mfb    = (const float*)d_in[17];
  const float* ln_fg  = (const float*)d_in[18];
  const float* ln_fb  = (const float*)d_in[19];
  const float* wqkv_e = (const float*)d_in[20];
  const float* bqkv_e = (const float*)d_in[21];
  const float* wo_e   = (const float*)d_in[22];
  const float* bo_e   = (const float*)d_in[23];
  const float* ln_eg  = (const float*)d_in[24];
  const float* ln_eb  = (const float*)d_in[25];
  const float* w_off  = (const float*)d_in[26];
  const float* b_off  = (const float*)d_in[27];
  const float* w_attn = (const float*)d_in[28];
  const float* b_attn = (const float*)d_in[29];
  const float* w_val  = (const float*)d_in[30];
  const float* b_val  = (const float*)d_in[31];
  const float* w_out  = (const float*)d_in[32];
  const float* b_out  = (const float*)d_in[33];
  const float* ln_cg  = (const float*)d_in[34];
  const float* ln_cb  = (const float*)d_in[35];
  const float* w1     = (const float*)d_in[36];
  const float* b1     = (const float*)d_in[37];
  const float* w2     = (const float*)d_in[38];
  const float* b2     = (const float*)d_in[39];
  const float* ln3g   = (const float*)d_in[40];
  const float* ln3b   = (const float*)d_in[41];

  float* out = (float*)d_out;

  // ---- workspace layout ----
  char* p = (char*)d_ws;
  auto alloc = [&](size_t bytes) {
    char* r = p; p += (bytes + 255) & ~(size_t)255; return r;
  };
  const size_t MCf = (size_t)M_ROWS * CDIM * 4;
  const size_t MCb = (size_t)M_ROWS * CDIM * 2;
  float* S0 = (float*)alloc(MCf);
  float* S1 = (float*)alloc(MCf);
  float* S2 = (float*)alloc(MCf);
  float* OA = (float*)alloc((size_t)M_ROWS * 384 * 4);
  u16* X0 = (u16*)alloc(MCb);
  u16* X1 = (u16*)alloc(MCb);
  u16* X2 = (u16*)alloc(MCb);
  u16* X3 = (u16*)alloc(MCb);
  u16* B768 = (u16*)alloc((size_t)M_ROWS * 768 * 2);
  u16* BB   = (u16*)alloc((size_t)M_ROWS * 1024 * 2);
  u16* SRCB = (u16*)alloc((size_t)SRC_PAD * CDIM * 2);
  u16* VB   = (u16*)alloc((size_t)SRC_PAD * CDIM * 2);
  u16* W_b  = (u16*)alloc(1343488 * 2);
  u16* wc_b = (u16*)alloc(589824 * 2);
  float* convScale = (float*)alloc(256 * 4);
  float* convShift = (float*)alloc(256 * 4);
  float* bcat      = (float*)alloc(384 * 4);
  const size_t needed = (size_t)(p - (char*)d_ws);
  if (ws_size < needed) {
    fprintf(stderr, "kernel_launch: workspace too small (%zu < %zu)\n",
            (size_t)ws_size, needed);
    return;
  }
  u16* wqkv_i_b = W_b + 0;
  u16* wo_i_b   = W_b + 196608;
  u16* mfw_b    = W_b + 262144;
  u16* wqkv_e_b = W_b + 327680;
  u16* wo_e_b   = W_b + 524288;
  u16* w_val_b  = W_b + 589824;
  u16* w_out_b  = W_b + 655360;
  u16* w1_b     = W_b + 720896;
  u16* w2_b     = W_b + 983040;
  u16* wcat_b   = W_b + 1245184;

  dim3 blk(256);
  auto gemm = [&](const u16* A, const u16* W, const float* bias,
                  float* Cf, u16* Cb, int M, int N, int K, int relu) {
    gemm64<0><<<dim3(N / 64, M / 64), blk, 0, stream>>>(
        A, W, bias, nullptr, Cf, Cb, M, N, K, relu);
  };

  // ---- preprocessing (4 dispatches) ----
  k_wcvt<<<dim3((167936 + 255) / 256), blk, 0, stream>>>(
      wqkv_i, wo_i, mfw, wqkv_e, wo_e, w_val, w_out, w1, w2, w_off, w_attn,
      (short8v*)W_b);
  k_convw<<<256, blk, 0, stream>>>(conv_w, wc_b);
  k_bnfold<<<1, dim3(384), 0, stream>>>(conv_b, bn_g, bn_b, bn_m, bn_v,
                                        b_off, b_attn, convScale, convShift, bcat);
  {
    int n8r = SRC_ROWS * CDIM / 8, n8t = SRC_PAD * CDIM / 8;
    k_src2b<<<dim3((n8t + 255) / 256), blk, 0, stream>>>(
        (const float4*)src, (short8v*)SRCB, n8r, n8t);
  }

  const int n8 = M_ROWS * CDIM / 8;

  // ---- EFSA intra branch ----
  k_qk<<<dim3((n8 + 255) / 256), blk, 0, stream>>>(
      (const float4*)tgt, (const float4*)qpos, (short8v*)X0, (short8v*)X1, n8);
  gemm(X0, wqkv_i_b, bqkv_i, nullptr, B768, M_ROWS, 512, 256, 0);      // Q|K
  gemm(X1, wqkv_i_b + 131072, bqkv_i + 512, nullptr, X2, M_ROWS, 256, 256, 0); // V
  k_attn_intra<<<800 * 8, blk, 0, stream>>>(B768, X2, X3);
  gemm(X3, wo_i_b, bo_i, S0, nullptr, M_ROWS, 256, 256, 0);            // t_attn
  gemm64<1><<<dim3(4, 200), blk, 0, stream>>>(                         // conv+BN+ReLU
      X0, wc_b, convShift, convScale, S1, nullptr, M_ROWS, 256, 2304, 1);
  k_ln<0><<<M_ROWS / 4, blk, 0, stream>>>(S0, S1, tgt, ln_ig, ln_ib,
                                          S2, X1, nullptr);            // tgt1
  gemm(X1, mfw_b, mfb, S0, nullptr, M_ROWS, 256, 256, 0);              // fuse tmp
  k_ln<1><<<M_ROWS / 4, blk, 0, stream>>>(S0, nullptr, S2, ln_fg, ln_fb,
                                          S1, X2, nullptr);            // tgt2 (ti)

  // ---- inter attention ----
  gemm(X2, wqkv_e_b, bqkv_e, nullptr, B768, M_ROWS, 768, 256, 0);      // QKV
  k_attn_inter<<<128 * 8, blk, 0, stream>>>(B768, X3);
  gemm(X3, wo_e_b, bo_e, S0, nullptr, M_ROWS, 256, 256, 0);            // t2
  k_ln<2><<<M_ROWS / 4, blk, 0, stream>>>(S1, S0, nullptr, ln_eg, ln_eb,
                                          S2, X0, qpos);               // tgt_inter; X0=q_cross

  // ---- deformable cross attention ----
  gemm128<<<dim3(2, SRC_PAD / 128), blk, 0, stream>>>(
      SRCB, w_val_b, b_val, nullptr, VB, SRC_PAD, 256, 256, 0);        // value bf16
  gemm(X0, wcat_b, bcat, OA, nullptr, M_ROWS, 384, 256, 0);            // off|aw
  k_msda<<<M_ROWS / 4, blk, 0, stream>>>(OA, ref, VB, X1);             // sampled bf16
  gemm(X1, w_out_b, b_out, S0, nullptr, M_ROWS, 256, 256, 0);          // t2c
  k_ln<0><<<M_ROWS / 4, blk, 0, stream>>>(S2, S0, nullptr, ln_cg, ln_cb,
                                          S1, X2, nullptr);            // tgt3

  // ---- FFN ----
  gemm(X2, w1_b, b1, nullptr, BB, M_ROWS, 1024, 256, 1);               // relu(h)
  gemm(BB, w2_b, b2, S0, nullptr, M_ROWS, 256, 1024, 0);               // t2f
  k_ln<0><<<M_ROWS / 4, blk, 0, stream>>>(S1, S0, nullptr, ln3g, ln3b,
                                          out, nullptr, nullptr);      // output
}